// Round 1
// baseline (5664.111 us; speedup 1.0000x reference)
//
#include <hip/hip_runtime.h>

// ---------------------------------------------------------------------------
// Graphormer forward, MI355X. Round 0: correctness-first f32 implementation.
// Structure: tiled f32 GEMM template (reg-tiled 8x8 / 4x4) with fused
// epilogues (bias / bias+residual / bias+gelu / attention-bias gather),
// LN kernel (wave-per-row), softmax kernel (block-per-row), degree atomics,
// per-layer edge-dot precompute. All launches on `stream`; scratch from d_ws.
// ---------------------------------------------------------------------------

constexpr int NN    = 2048;   // nodes
constexpr int EE    = 32768;  // edges
constexpr int IN_ND = 128;
constexpr int ND    = 256;
constexpr int IN_ED = 64;
constexpr int ED    = 128;
constexpr int H     = 8;
constexpr int FF    = 1024;
constexpr int NL    = 3;
constexpr int LMAX  = 5;
constexpr int MAXDEG= 64;

enum { B_NORMAL = 0, B_TRANS = 1, B_HEADPACK = 2 };
enum { E_NONE = 0, E_BIAS = 1, E_BIAS_RES = 2, E_BIAS_GELU = 3, E_ATTN = 4 };

__device__ __forceinline__ float gelu_f(float x) {
    return 0.5f * x * (1.0f + erff(x * 0.70710678118654752440f));
}

// ---------------------------------------------------------------------------
// Generic tiled f32 GEMM: C[row,col] = epilogue( sum_k A[row,k]*B[k,col] )
//  - BMODE selects B addressing: normal row-major [K,N]; transposed [N,K]
//    (for Q·K^T); head-packed Wq/Wk/Wv layout [H, ND(d), ND(k)] addressed as
//    logical [K=ND, N=H*ND].
//  - blockIdx.z gives an optional "head" dimension via aZs/bZs/cZs/dZs strides.
// All M,N,K used in this problem are exact multiples of the tiles (no guards).
// ---------------------------------------------------------------------------
template<int TM, int TN, int MT, int NT, int BMODE, int EPI>
__global__ __launch_bounds__(256)
void gemm_k(const float* __restrict__ A, int lda, long aZs,
            const float* __restrict__ B, int ldb, long bZs,
            float* __restrict__ C, int ldc, long cZs,
            int K,
            const float* __restrict__ bias,
            float scale,
            const int* __restrict__ ndist,
            const int* __restrict__ epaths,
            const float* __restrict__ bspat,
            const float* __restrict__ dots, long dZs)
{
    static_assert((TM / MT) * (TN / NT) == 256, "256 threads");
    constexpr int BKv = 8;
    const int z = blockIdx.z;
    A += (long)z * aZs;
    B += (long)z * bZs;
    C += (long)z * cZs;
    const float* dots_h = dots + (long)z * dZs;

    const int row0 = blockIdx.y * TM;
    const int col0 = blockIdx.x * TN;
    constexpr int TX = TN / NT;
    const int tid = threadIdx.x;
    const int tx = tid % TX;
    const int ty = tid / TX;

    __shared__ float As[BKv][TM];
    __shared__ float Bs[BKv][TN];

    float acc[MT][NT];
#pragma unroll
    for (int i = 0; i < MT; i++)
#pragma unroll
        for (int j = 0; j < NT; j++) acc[i][j] = 0.f;

    for (int k0 = 0; k0 < K; k0 += BKv) {
        // ---- stage A tile (TM x 8), k-contiguous global reads ----
        if constexpr (TM == 128) {
            const int r = tid >> 1, kk = (tid & 1) * 4;
            const float4 av = *reinterpret_cast<const float4*>(
                A + (long)(row0 + r) * lda + (k0 + kk));
            As[kk + 0][r] = av.x; As[kk + 1][r] = av.y;
            As[kk + 2][r] = av.z; As[kk + 3][r] = av.w;
        } else {  // TM == 64
            const int r = tid >> 2, kk = (tid & 3) * 2;
            const float2 av = *reinterpret_cast<const float2*>(
                A + (long)(row0 + r) * lda + (k0 + kk));
            As[kk + 0][r] = av.x; As[kk + 1][r] = av.y;
        }
        // ---- stage B tile (8 x TN) ----
        if constexpr (BMODE == B_TRANS) {
            if constexpr (TN == 128) {
                const int c = tid >> 1, kk = (tid & 1) * 4;
                const float4 bv = *reinterpret_cast<const float4*>(
                    B + (long)(col0 + c) * ldb + (k0 + kk));
                Bs[kk + 0][c] = bv.x; Bs[kk + 1][c] = bv.y;
                Bs[kk + 2][c] = bv.z; Bs[kk + 3][c] = bv.w;
            } else {
                const int c = tid >> 2, kk = (tid & 3) * 2;
                const float2 bv = *reinterpret_cast<const float2*>(
                    B + (long)(col0 + c) * ldb + (k0 + kk));
                Bs[kk + 0][c] = bv.x; Bs[kk + 1][c] = bv.y;
            }
        } else {
            if constexpr (TN == 128) {
                const int kk = tid >> 5, c = (tid & 31) * 4;
                long idx;
                if constexpr (BMODE == B_HEADPACK)
                    idx = (long)(col0 >> 8) * (ND * ND) + (long)(k0 + kk) * ND
                          + (col0 & 255) + c;
                else
                    idx = (long)(k0 + kk) * ldb + col0 + c;
                const float4 bv = *reinterpret_cast<const float4*>(B + idx);
                *reinterpret_cast<float4*>(&Bs[kk][c]) = bv;
            } else {
                const int kk = tid >> 5, c = (tid & 31) * 2;
                long idx;
                if constexpr (BMODE == B_HEADPACK)
                    idx = (long)(col0 >> 8) * (ND * ND) + (long)(k0 + kk) * ND
                          + (col0 & 255) + c;
                else
                    idx = (long)(k0 + kk) * ldb + col0 + c;
                const float2 bv = *reinterpret_cast<const float2*>(B + idx);
                Bs[kk][c] = bv.x; Bs[kk][c + 1] = bv.y;
            }
        }
        __syncthreads();
        // ---- compute ----
#pragma unroll
        for (int kk = 0; kk < BKv; kk++) {
            float a[MT], b[NT];
#pragma unroll
            for (int i = 0; i < MT; i++) a[i] = As[kk][ty * MT + i];
#pragma unroll
            for (int j = 0; j < NT; j++) b[j] = Bs[kk][tx * NT + j];
#pragma unroll
            for (int i = 0; i < MT; i++)
#pragma unroll
                for (int j = 0; j < NT; j++)
                    acc[i][j] = fmaf(a[i], b[j], acc[i][j]);
        }
        __syncthreads();
    }

    // ---- epilogue ----
#pragma unroll
    for (int i = 0; i < MT; i++) {
        const int row = row0 + ty * MT + i;
        float vals[NT];
#pragma unroll
        for (int j = 0; j < NT; j++) {
            const int col = col0 + tx * NT + j;
            float v = acc[i][j];
            if constexpr (EPI == E_BIAS) {
                v += bias[col];
            } else if constexpr (EPI == E_BIAS_RES) {
                v += bias[col] + C[(long)row * ldc + col];
            } else if constexpr (EPI == E_BIAS_GELU) {
                v = gelu_f(v + bias[col]);
            } else if constexpr (EPI == E_ATTN) {
                // scores[n][m] = acc*scale + b_spatial_term + path_edge_term
                const int n = row, m = col;
                const int d = ndist[(long)n * NN + m];
                float bb = 0.f, cc = 0.f;
                if (d > 0) bb = bspat[(d < LMAX ? d : LMAX) - 1];
                int npe = d - 1;
                npe = npe < 0 ? 0 : (npe > LMAX ? LMAX : npe);
                if (npe > 0) {
                    const int* ep = epaths + ((long)n * NN + m) * LMAX;
                    for (int s = 0; s < npe; s++) cc += dots_h[s * EE + ep[s]];
                    cc *= (1.f / (float)npe);
                }
                v = v * scale + bb + cc;
            }
            vals[j] = v;
        }
        float* cp = C + (long)row * ldc + col0 + tx * NT;
        if constexpr (NT == 8) {
            *reinterpret_cast<float4*>(cp)     = make_float4(vals[0], vals[1], vals[2], vals[3]);
            *reinterpret_cast<float4*>(cp + 4) = make_float4(vals[4], vals[5], vals[6], vals[7]);
        } else {
            *reinterpret_cast<float4*>(cp)     = make_float4(vals[0], vals[1], vals[2], vals[3]);
        }
    }
}

// ---------------------------------------------------------------------------
// LayerNorm over rows of width ND=256: one wave per row (4 rows / block).
// ---------------------------------------------------------------------------
__global__ __launch_bounds__(256)
void ln_k(const float* __restrict__ x, const float* __restrict__ w,
          const float* __restrict__ b, float* __restrict__ y)
{
    const int wid = threadIdx.x >> 6, lane = threadIdx.x & 63;
    const int row = blockIdx.x * 4 + wid;
    const float4 v = reinterpret_cast<const float4*>(x + (long)row * ND)[lane];
    float s = v.x + v.y + v.z + v.w;
#pragma unroll
    for (int o = 32; o >= 1; o >>= 1) s += __shfl_xor(s, o);
    const float mean = s * (1.f / ND);
    const float d0 = v.x - mean, d1 = v.y - mean, d2 = v.z - mean, d3 = v.w - mean;
    float sq = d0 * d0 + d1 * d1 + d2 * d2 + d3 * d3;
#pragma unroll
    for (int o = 32; o >= 1; o >>= 1) sq += __shfl_xor(sq, o);
    const float rstd = rsqrtf(sq * (1.f / ND) + 1e-5f);
    const float4 wv = reinterpret_cast<const float4*>(w)[lane];
    const float4 bv = reinterpret_cast<const float4*>(b)[lane];
    float4 o4;
    o4.x = d0 * rstd * wv.x + bv.x;
    o4.y = d1 * rstd * wv.y + bv.y;
    o4.z = d2 * rstd * wv.z + bv.z;
    o4.w = d3 * rstd * wv.w + bv.w;
    reinterpret_cast<float4*>(y + (long)row * ND)[lane] = o4;
}

// ---------------------------------------------------------------------------
// Row softmax over width NN=2048, in place. grid (NN, 1, heads).
// ---------------------------------------------------------------------------
__global__ __launch_bounds__(256)
void softmax_k(float* __restrict__ sc, long zstride)
{
    float* r = sc + (long)blockIdx.z * zstride + (long)blockIdx.x * NN;
    const int t = threadIdx.x;
    float4 v0 = reinterpret_cast<float4*>(r)[t];
    float4 v1 = reinterpret_cast<float4*>(r)[t + 256];
    float m = fmaxf(fmaxf(fmaxf(v0.x, v0.y), fmaxf(v0.z, v0.w)),
                    fmaxf(fmaxf(v1.x, v1.y), fmaxf(v1.z, v1.w)));
    __shared__ float red[4];
#pragma unroll
    for (int o = 32; o >= 1; o >>= 1) m = fmaxf(m, __shfl_xor(m, o));
    if ((t & 63) == 0) red[t >> 6] = m;
    __syncthreads();
    m = fmaxf(fmaxf(red[0], red[1]), fmaxf(red[2], red[3]));
    __syncthreads();
    v0.x = expf(v0.x - m); v0.y = expf(v0.y - m);
    v0.z = expf(v0.z - m); v0.w = expf(v0.w - m);
    v1.x = expf(v1.x - m); v1.y = expf(v1.y - m);
    v1.z = expf(v1.z - m); v1.w = expf(v1.w - m);
    float s = v0.x + v0.y + v0.z + v0.w + v1.x + v1.y + v1.z + v1.w;
#pragma unroll
    for (int o = 32; o >= 1; o >>= 1) s += __shfl_xor(s, o);
    if ((t & 63) == 0) red[t >> 6] = s;
    __syncthreads();
    s = red[0] + red[1] + red[2] + red[3];
    const float inv = 1.f / s;
    v0.x *= inv; v0.y *= inv; v0.z *= inv; v0.w *= inv;
    v1.x *= inv; v1.y *= inv; v1.z *= inv; v1.w *= inv;
    reinterpret_cast<float4*>(r)[t]       = v0;
    reinterpret_cast<float4*>(r)[t + 256] = v1;
}

// ---------------------------------------------------------------------------
// Edge-dot precompute: dots[p=h*L+s][e] = edge_vec_l[p,:] . e_feat[e,:]
// grid (EE/256, H*LMAX)
// ---------------------------------------------------------------------------
__global__ __launch_bounds__(256)
void dots_k(const float* __restrict__ e, const float* __restrict__ ev,
            float* __restrict__ dots)
{
    const int p = blockIdx.y;
    const int ei = blockIdx.x * 256 + threadIdx.x;
    __shared__ float evs[ED];
    if (threadIdx.x < ED) evs[threadIdx.x] = ev[p * ED + threadIdx.x];
    __syncthreads();
    const float4* er = reinterpret_cast<const float4*>(e + (long)ei * ED);
    float s = 0.f;
#pragma unroll
    for (int d4 = 0; d4 < ED / 4; d4++) {
        const float4 t = er[d4];
        s += evs[d4 * 4 + 0] * t.x + evs[d4 * 4 + 1] * t.y
           + evs[d4 * 4 + 2] * t.z + evs[d4 * 4 + 3] * t.w;
    }
    dots[(long)p * EE + ei] = s;
}

__global__ void deg_k(const int* __restrict__ ei, int* __restrict__ ind,
                      int* __restrict__ outd)
{
    const int e = blockIdx.x * 256 + threadIdx.x;
    atomicAdd(&outd[ei[e]], 1);        // edge_index[0] = src
    atomicAdd(&ind[ei[EE + e]], 1);    // edge_index[1] = dst
}

__global__ void degembed_k(float* __restrict__ h, const int* __restrict__ ind,
                           const int* __restrict__ outd,
                           const float* __restrict__ z_in,
                           const float* __restrict__ z_out)
{
    const int idx = blockIdx.x * 256 + threadIdx.x;
    const int n = idx >> 8, c = idx & 255;
    int di = ind[n];  di = di > (MAXDEG - 1) ? (MAXDEG - 1) : di;
    int dw = outd[n]; dw = dw > (MAXDEG - 1) ? (MAXDEG - 1) : dw;
    h[idx] += z_in[di * ND + c] + z_out[dw * ND + c];
}

__global__ void sentinel_k(float* o) { o[0] = 12345.0f; }  // ws too small marker

// ---------------------------------------------------------------------------
extern "C" void kernel_launch(void* const* d_in, const int* in_sizes, int n_in,
                              void* d_out, int out_size, void* d_ws, size_t ws_size,
                              hipStream_t stream)
{
    const float* x      = (const float*)d_in[0];
    const int*   eidx   = (const int*)d_in[1];
    const float* eattr  = (const float*)d_in[2];
    const int*   ndist  = (const int*)d_in[3];
    const int*   epaths = (const int*)d_in[4];
    const float* Wn_in  = (const float*)d_in[5];
    const float* bn_in  = (const float*)d_in[6];
    const float* We_in  = (const float*)d_in[7];
    const float* be_in  = (const float*)d_in[8];
    const float* z_in   = (const float*)d_in[9];
    const float* z_out  = (const float*)d_in[10];
    const float* bspat  = (const float*)d_in[11];
    const float* ln1w   = (const float*)d_in[12];
    const float* ln1b   = (const float*)d_in[13];
    const float* ln2w   = (const float*)d_in[14];
    const float* ln2b   = (const float*)d_in[15];
    const float* Wq     = (const float*)d_in[16];
    const float* bq     = (const float*)d_in[17];
    const float* Wk     = (const float*)d_in[18];
    const float* bk     = (const float*)d_in[19];
    const float* Wv     = (const float*)d_in[20];
    const float* bv     = (const float*)d_in[21];
    const float* evec   = (const float*)d_in[22];
    const float* Wo     = (const float*)d_in[23];
    const float* bo     = (const float*)d_in[24];
    const float* Wff1   = (const float*)d_in[25];
    const float* bff1   = (const float*)d_in[26];
    const float* Wff2   = (const float*)d_in[27];
    const float* bff2   = (const float*)d_in[28];
    const float* Wout   = (const float*)d_in[29];
    const float* bout   = (const float*)d_in[30];
    float* out = (float*)d_out;

    // ---- workspace carve-up ----
    char* p = (char*)d_ws;
    auto alloc = [&](size_t bytes) -> char* {
        char* r = p;
        p += (bytes + 255) & ~(size_t)255;
        return r;
    };
    float* h    = (float*)alloc((size_t)NN * ND * 4);       //  2 MB
    float* xn   = (float*)alloc((size_t)NN * ND * 4);       //  2 MB
    float* e    = (float*)alloc((size_t)EE * ED * 4);       // 16 MB
    float* qb   = (float*)alloc((size_t)NN * H * ND * 4);   // 16 MB  [n][h*256+k]
    float* kb   = (float*)alloc((size_t)NN * H * ND * 4);   // 16 MB
    float* vb   = (float*)alloc((size_t)NN * H * ND * 4);   // 16 MB
    float* o2   = (float*)alloc((size_t)NN * H * ND * 4);   // 16 MB
    float* ff1  = (float*)alloc((size_t)NN * FF * 4);       //  8 MB
    float* dots = (float*)alloc((size_t)H * LMAX * EE * 4); //  5 MB
    int*   ind  = (int*)alloc(NN * 4);
    int*   outd = (int*)alloc(NN * 4);
    const size_t base_need = (size_t)(p - (char*)d_ws);
    const size_t sc_all = (size_t)H * NN * NN * 4;          // 134 MB
    const size_t sc_one = (size_t)NN * NN * 4;              // 16.8 MB
    bool allheads;
    float* scores;
    if (ws_size >= base_need + sc_all) {
        allheads = true;  scores = (float*)alloc(sc_all);
    } else if (ws_size >= base_need + sc_one) {
        allheads = false; scores = (float*)alloc(sc_one);
    } else {
        sentinel_k<<<1, 1, 0, stream>>>(out);
        return;
    }

    const float* nul = nullptr;
    const long NN2 = (long)NN * NN;

    // ---- degrees + input projections ----
    hipMemsetAsync(ind, 0, NN * 4, stream);
    hipMemsetAsync(outd, 0, NN * 4, stream);
    deg_k<<<EE / 256, 256, 0, stream>>>(eidx, ind, outd);

    gemm_k<64, 64, 4, 4, B_NORMAL, E_BIAS><<<dim3(ND / 64, NN / 64), 256, 0, stream>>>(
        x, IN_ND, 0, Wn_in, ND, 0, h, ND, 0, IN_ND, bn_in, 1.f,
        ndist, epaths, bspat, dots, 0);
    degembed_k<<<NN * ND / 256, 256, 0, stream>>>(h, ind, outd, z_in, z_out);

    gemm_k<64, 64, 4, 4, B_NORMAL, E_BIAS><<<dim3(ED / 64, EE / 64), 256, 0, stream>>>(
        eattr, IN_ED, 0, We_in, ED, 0, e, ED, 0, IN_ED, be_in, 1.f,
        ndist, epaths, bspat, dots, 0);

    const float scale = 1.f / 16.f;  // 1/sqrt(dk=256)

    for (int l = 0; l < NL; l++) {
        ln_k<<<NN / 4, 256, 0, stream>>>(h, ln1w + l * ND, ln1b + l * ND, xn);

        // Q/K/V: [2048,256] @ headpacked [256, 2048] -> [n][h*256+k]
        gemm_k<128, 128, 8, 8, B_HEADPACK, E_BIAS><<<dim3(H * ND / 128, NN / 128), 256, 0, stream>>>(
            xn, ND, 0, Wq + (size_t)l * H * ND * ND, 0, 0, qb, H * ND, 0, ND,
            bq + l * H * ND, 1.f, ndist, epaths, bspat, dots, 0);
        gemm_k<128, 128, 8, 8, B_HEADPACK, E_BIAS><<<dim3(H * ND / 128, NN / 128), 256, 0, stream>>>(
            xn, ND, 0, Wk + (size_t)l * H * ND * ND, 0, 0, kb, H * ND, 0, ND,
            bk + l * H * ND, 1.f, ndist, epaths, bspat, dots, 0);
        gemm_k<128, 128, 8, 8, B_HEADPACK, E_BIAS><<<dim3(H * ND / 128, NN / 128), 256, 0, stream>>>(
            xn, ND, 0, Wv + (size_t)l * H * ND * ND, 0, 0, vb, H * ND, 0, ND,
            bv + l * H * ND, 1.f, ndist, epaths, bspat, dots, 0);

        dots_k<<<dim3(EE / 256, H * LMAX), 256, 0, stream>>>(
            e, evec + (size_t)l * H * LMAX * ED, dots);

        if (allheads) {
            gemm_k<128, 128, 8, 8, B_TRANS, E_ATTN><<<dim3(NN / 128, NN / 128, H), 256, 0, stream>>>(
                qb, H * ND, ND, kb, H * ND, ND, scores, NN, NN2, ND,
                nul, scale, ndist, epaths, bspat, dots, (long)LMAX * EE);
            softmax_k<<<dim3(NN, 1, H), 256, 0, stream>>>(scores, NN2);
            gemm_k<128, 64, 8, 4, B_NORMAL, E_NONE><<<dim3(ND / 64, NN / 128, H), 256, 0, stream>>>(
                scores, NN, NN2, vb, H * ND, ND, o2, H * ND, ND, NN,
                nul, 1.f, ndist, epaths, bspat, dots, 0);
        } else {
            for (int hh = 0; hh < H; hh++) {
                gemm_k<128, 128, 8, 8, B_TRANS, E_ATTN><<<dim3(NN / 128, NN / 128, 1), 256, 0, stream>>>(
                    qb + hh * ND, H * ND, 0, kb + hh * ND, H * ND, 0, scores, NN, 0, ND,
                    nul, scale, ndist, epaths, bspat, dots + (long)hh * LMAX * EE, 0);
                softmax_k<<<dim3(NN, 1, 1), 256, 0, stream>>>(scores, 0);
                gemm_k<128, 64, 8, 4, B_NORMAL, E_NONE><<<dim3(ND / 64, NN / 128, 1), 256, 0, stream>>>(
                    scores, NN, 0, vb + hh * ND, H * ND, 0, o2 + hh * ND, H * ND, 0, NN,
                    nul, 1.f, ndist, epaths, bspat, dots, 0);
            }
        }

        // h = o2 @ Wo[l] + bo[l] + h
        gemm_k<64, 64, 4, 4, B_NORMAL, E_BIAS_RES><<<dim3(ND / 64, NN / 64), 256, 0, stream>>>(
            o2, H * ND, 0, Wo + (size_t)l * H * ND * ND, ND, 0, h, ND, 0, H * ND,
            bo + l * ND, 1.f, ndist, epaths, bspat, dots, 0);

        ln_k<<<NN / 4, 256, 0, stream>>>(h, ln2w + l * ND, ln2b + l * ND, xn);

        gemm_k<128, 128, 8, 8, B_NORMAL, E_BIAS_GELU><<<dim3(FF / 128, NN / 128), 256, 0, stream>>>(
            xn, ND, 0, Wff1 + (size_t)l * ND * FF, FF, 0, ff1, FF, 0, ND,
            bff1 + l * FF, 1.f, ndist, epaths, bspat, dots, 0);
        gemm_k<64, 64, 4, 4, B_NORMAL, E_BIAS_RES><<<dim3(ND / 64, NN / 64), 256, 0, stream>>>(
            ff1, FF, 0, Wff2 + (size_t)l * FF * ND, ND, 0, h, ND, 0, FF,
            bff2 + l * ND, 1.f, ndist, epaths, bspat, dots, 0);
    }

    gemm_k<64, 64, 4, 4, B_NORMAL, E_BIAS><<<dim3(ND / 64, NN / 64), 256, 0, stream>>>(
        h, ND, 0, Wout, ND, 0, out, ND, 0, ND, bout, 1.f,
        ndist, epaths, bspat, dots, 0);
}

// Round 2
// 3710.812 us; speedup vs baseline: 1.5264x; 1.5264x over previous
//
#include <hip/hip_runtime.h>

// ---------------------------------------------------------------------------
// Graphormer forward, MI355X. Round 1: split attention-bias gather out of the
// QK^T epilogue. dots transposed to [s][e][h] so one 32B gather serves all 8
// heads; bias written into scores, QK^T accumulates on top (E_ACC epilogue).
// GEMM inner loop now uses float4 LDS fragment reads.
// ---------------------------------------------------------------------------

constexpr int NN    = 2048;   // nodes
constexpr int EE    = 32768;  // edges
constexpr int IN_ND = 128;
constexpr int ND    = 256;
constexpr int IN_ED = 64;
constexpr int ED    = 128;
constexpr int H     = 8;
constexpr int FF    = 1024;
constexpr int NL    = 3;
constexpr int LMAX  = 5;
constexpr int MAXDEG= 64;

enum { B_NORMAL = 0, B_TRANS = 1, B_HEADPACK = 2 };
enum { E_NONE = 0, E_BIAS = 1, E_BIAS_RES = 2, E_BIAS_GELU = 3, E_ACC = 4 };

__device__ __forceinline__ float gelu_f(float x) {
    return 0.5f * x * (1.0f + erff(x * 0.70710678118654752440f));
}

// ---------------------------------------------------------------------------
// Generic tiled f32 GEMM: C[row,col] = epilogue( sum_k A[row,k]*B[k,col] )
// E_ACC: C = C_prev + acc*scale  (QK^T accumulating onto precomputed bias)
// ---------------------------------------------------------------------------
template<int TM, int TN, int MT, int NT, int BMODE, int EPI>
__global__ __launch_bounds__(256)
void gemm_k(const float* __restrict__ A, int lda, long aZs,
            const float* __restrict__ B, int ldb, long bZs,
            float* __restrict__ C, int ldc, long cZs,
            int K,
            const float* __restrict__ bias,
            float scale)
{
    static_assert((TM / MT) * (TN / NT) == 256, "256 threads");
    constexpr int BKv = 8;
    const int z = blockIdx.z;
    A += (long)z * aZs;
    B += (long)z * bZs;
    C += (long)z * cZs;

    const int row0 = blockIdx.y * TM;
    const int col0 = blockIdx.x * TN;
    constexpr int TX = TN / NT;
    const int tid = threadIdx.x;
    const int tx = tid % TX;
    const int ty = tid / TX;

    __shared__ float As[BKv][TM];
    __shared__ float Bs[BKv][TN];

    float acc[MT][NT];
#pragma unroll
    for (int i = 0; i < MT; i++)
#pragma unroll
        for (int j = 0; j < NT; j++) acc[i][j] = 0.f;

    for (int k0 = 0; k0 < K; k0 += BKv) {
        // ---- stage A tile (TM x 8), k-contiguous global reads ----
        if constexpr (TM == 128) {
            const int r = tid >> 1, kk = (tid & 1) * 4;
            const float4 av = *reinterpret_cast<const float4*>(
                A + (long)(row0 + r) * lda + (k0 + kk));
            As[kk + 0][r] = av.x; As[kk + 1][r] = av.y;
            As[kk + 2][r] = av.z; As[kk + 3][r] = av.w;
        } else {  // TM == 64
            const int r = tid >> 2, kk = (tid & 3) * 2;
            const float2 av = *reinterpret_cast<const float2*>(
                A + (long)(row0 + r) * lda + (k0 + kk));
            As[kk + 0][r] = av.x; As[kk + 1][r] = av.y;
        }
        // ---- stage B tile (8 x TN) ----
        if constexpr (BMODE == B_TRANS) {
            if constexpr (TN == 128) {
                const int c = tid >> 1, kk = (tid & 1) * 4;
                const float4 bv = *reinterpret_cast<const float4*>(
                    B + (long)(col0 + c) * ldb + (k0 + kk));
                Bs[kk + 0][c] = bv.x; Bs[kk + 1][c] = bv.y;
                Bs[kk + 2][c] = bv.z; Bs[kk + 3][c] = bv.w;
            } else {
                const int c = tid >> 2, kk = (tid & 3) * 2;
                const float2 bv = *reinterpret_cast<const float2*>(
                    B + (long)(col0 + c) * ldb + (k0 + kk));
                Bs[kk + 0][c] = bv.x; Bs[kk + 1][c] = bv.y;
            }
        } else {
            if constexpr (TN == 128) {
                const int kk = tid >> 5, c = (tid & 31) * 4;
                long idx;
                if constexpr (BMODE == B_HEADPACK)
                    idx = (long)(col0 >> 8) * (ND * ND) + (long)(k0 + kk) * ND
                          + (col0 & 255) + c;
                else
                    idx = (long)(k0 + kk) * ldb + col0 + c;
                const float4 bv = *reinterpret_cast<const float4*>(B + idx);
                *reinterpret_cast<float4*>(&Bs[kk][c]) = bv;
            } else {
                const int kk = tid >> 5, c = (tid & 31) * 2;
                long idx;
                if constexpr (BMODE == B_HEADPACK)
                    idx = (long)(col0 >> 8) * (ND * ND) + (long)(k0 + kk) * ND
                          + (col0 & 255) + c;
                else
                    idx = (long)(k0 + kk) * ldb + col0 + c;
                const float2 bv = *reinterpret_cast<const float2*>(B + idx);
                Bs[kk][c] = bv.x; Bs[kk][c + 1] = bv.y;
            }
        }
        __syncthreads();
        // ---- compute (float4 LDS fragment reads) ----
#pragma unroll
        for (int kk = 0; kk < BKv; kk++) {
            float a[MT], b[NT];
            if constexpr (MT == 8) {
                *reinterpret_cast<float4*>(&a[0]) =
                    *reinterpret_cast<const float4*>(&As[kk][ty * MT]);
                *reinterpret_cast<float4*>(&a[4]) =
                    *reinterpret_cast<const float4*>(&As[kk][ty * MT + 4]);
            } else {
                *reinterpret_cast<float4*>(&a[0]) =
                    *reinterpret_cast<const float4*>(&As[kk][ty * MT]);
            }
            if constexpr (NT == 8) {
                *reinterpret_cast<float4*>(&b[0]) =
                    *reinterpret_cast<const float4*>(&Bs[kk][tx * NT]);
                *reinterpret_cast<float4*>(&b[4]) =
                    *reinterpret_cast<const float4*>(&Bs[kk][tx * NT + 4]);
            } else {
                *reinterpret_cast<float4*>(&b[0]) =
                    *reinterpret_cast<const float4*>(&Bs[kk][tx * NT]);
            }
#pragma unroll
            for (int i = 0; i < MT; i++)
#pragma unroll
                for (int j = 0; j < NT; j++)
                    acc[i][j] = fmaf(a[i], b[j], acc[i][j]);
        }
        __syncthreads();
    }

    // ---- epilogue ----
#pragma unroll
    for (int i = 0; i < MT; i++) {
        const int row = row0 + ty * MT + i;
        float vals[NT];
#pragma unroll
        for (int j = 0; j < NT; j++) {
            const int col = col0 + tx * NT + j;
            float v = acc[i][j];
            if constexpr (EPI == E_BIAS) {
                v += bias[col];
            } else if constexpr (EPI == E_BIAS_RES) {
                v += bias[col] + C[(long)row * ldc + col];
            } else if constexpr (EPI == E_BIAS_GELU) {
                v = gelu_f(v + bias[col]);
            } else if constexpr (EPI == E_ACC) {
                v = v * scale + C[(long)row * ldc + col];
            }
            vals[j] = v;
        }
        float* cp = C + (long)row * ldc + col0 + tx * NT;
        if constexpr (NT == 8) {
            *reinterpret_cast<float4*>(cp)     = make_float4(vals[0], vals[1], vals[2], vals[3]);
            *reinterpret_cast<float4*>(cp + 4) = make_float4(vals[4], vals[5], vals[6], vals[7]);
        } else {
            *reinterpret_cast<float4*>(cp)     = make_float4(vals[0], vals[1], vals[2], vals[3]);
        }
    }
}

// ---------------------------------------------------------------------------
// LayerNorm over rows of width ND=256: one wave per row (4 rows / block).
// ---------------------------------------------------------------------------
__global__ __launch_bounds__(256)
void ln_k(const float* __restrict__ x, const float* __restrict__ w,
          const float* __restrict__ b, float* __restrict__ y)
{
    const int wid = threadIdx.x >> 6, lane = threadIdx.x & 63;
    const int row = blockIdx.x * 4 + wid;
    const float4 v = reinterpret_cast<const float4*>(x + (long)row * ND)[lane];
    float s = v.x + v.y + v.z + v.w;
#pragma unroll
    for (int o = 32; o >= 1; o >>= 1) s += __shfl_xor(s, o);
    const float mean = s * (1.f / ND);
    const float d0 = v.x - mean, d1 = v.y - mean, d2 = v.z - mean, d3 = v.w - mean;
    float sq = d0 * d0 + d1 * d1 + d2 * d2 + d3 * d3;
#pragma unroll
    for (int o = 32; o >= 1; o >>= 1) sq += __shfl_xor(sq, o);
    const float rstd = rsqrtf(sq * (1.f / ND) + 1e-5f);
    const float4 wv = reinterpret_cast<const float4*>(w)[lane];
    const float4 bv = reinterpret_cast<const float4*>(b)[lane];
    float4 o4;
    o4.x = d0 * rstd * wv.x + bv.x;
    o4.y = d1 * rstd * wv.y + bv.y;
    o4.z = d2 * rstd * wv.z + bv.z;
    o4.w = d3 * rstd * wv.w + bv.w;
    reinterpret_cast<float4*>(y + (long)row * ND)[lane] = o4;
}

// ---------------------------------------------------------------------------
// Row softmax over width NN=2048, in place. grid (NN, 1, heads).
// ---------------------------------------------------------------------------
__global__ __launch_bounds__(256)
void softmax_k(float* __restrict__ sc, long zstride)
{
    float* r = sc + (long)blockIdx.z * zstride + (long)blockIdx.x * NN;
    const int t = threadIdx.x;
    float4 v0 = reinterpret_cast<float4*>(r)[t];
    float4 v1 = reinterpret_cast<float4*>(r)[t + 256];
    float m = fmaxf(fmaxf(fmaxf(v0.x, v0.y), fmaxf(v0.z, v0.w)),
                    fmaxf(fmaxf(v1.x, v1.y), fmaxf(v1.z, v1.w)));
    __shared__ float red[4];
#pragma unroll
    for (int o = 32; o >= 1; o >>= 1) m = fmaxf(m, __shfl_xor(m, o));
    if ((t & 63) == 0) red[t >> 6] = m;
    __syncthreads();
    m = fmaxf(fmaxf(red[0], red[1]), fmaxf(red[2], red[3]));
    __syncthreads();
    v0.x = expf(v0.x - m); v0.y = expf(v0.y - m);
    v0.z = expf(v0.z - m); v0.w = expf(v0.w - m);
    v1.x = expf(v1.x - m); v1.y = expf(v1.y - m);
    v1.z = expf(v1.z - m); v1.w = expf(v1.w - m);
    float s = v0.x + v0.y + v0.z + v0.w + v1.x + v1.y + v1.z + v1.w;
#pragma unroll
    for (int o = 32; o >= 1; o >>= 1) s += __shfl_xor(s, o);
    if ((t & 63) == 0) red[t >> 6] = s;
    __syncthreads();
    s = red[0] + red[1] + red[2] + red[3];
    const float inv = 1.f / s;
    v0.x *= inv; v0.y *= inv; v0.z *= inv; v0.w *= inv;
    v1.x *= inv; v1.y *= inv; v1.z *= inv; v1.w *= inv;
    reinterpret_cast<float4*>(r)[t]       = v0;
    reinterpret_cast<float4*>(r)[t + 256] = v1;
}

// ---------------------------------------------------------------------------
// Edge-dot precompute, head-transposed: dt[s][e][h] = evec_l[h,s,:] . e[e,:]
// One thread per (s,e); all 8 heads accumulated in registers; 32B store.
// grid (EE/256, LMAX)
// ---------------------------------------------------------------------------
__global__ __launch_bounds__(256)
void dotsT_k(const float* __restrict__ e, const float* __restrict__ evl,
             float* __restrict__ dt)
{
    const int s = blockIdx.y;
    const int ei = blockIdx.x * 256 + threadIdx.x;
    __shared__ float evs[H * ED];
    for (int i = threadIdx.x; i < H * ED; i += 256) {
        const int h = i >> 7, d = i & 127;   // ED=128
        evs[i] = evl[(h * LMAX + s) * ED + d];
    }
    __syncthreads();
    const float4* er = reinterpret_cast<const float4*>(e + (long)ei * ED);
    float c[H];
#pragma unroll
    for (int h = 0; h < H; h++) c[h] = 0.f;
#pragma unroll
    for (int d4 = 0; d4 < ED / 4; d4++) {
        const float4 t = er[d4];
#pragma unroll
        for (int h = 0; h < H; h++) {
            const float* w = &evs[h * ED + d4 * 4];
            c[h] += w[0] * t.x + w[1] * t.y + w[2] * t.z + w[3] * t.w;
        }
    }
    float4* o = reinterpret_cast<float4*>(dt + ((long)s * EE + ei) * H);
    o[0] = make_float4(c[0], c[1], c[2], c[3]);
    o[1] = make_float4(c[4], c[5], c[6], c[7]);
}

// ---------------------------------------------------------------------------
// Attention bias: scores[h][n][m] = b_mat[n,m] + c[h,n,m]  (pre-QK^T init)
// One thread per (n,m); one 32B gather per path step serves all 8 heads.
// hsel >= 0: single-head fallback (write scores[n][m] for that head only).
// ---------------------------------------------------------------------------
__global__ __launch_bounds__(256)
void bias_k(const int* __restrict__ ndist, const int* __restrict__ epaths,
            const float* __restrict__ bspat, const float* __restrict__ dt,
            float* __restrict__ scores, int hsel)
{
    const long idx = (long)blockIdx.x * 256 + threadIdx.x;
    const int d = ndist[idx];
    float bb = 0.f;
    if (d > 0) bb = bspat[(d < LMAX ? d : LMAX) - 1];
    int npe = d - 1;
    npe = npe < 0 ? 0 : (npe > LMAX ? LMAX : npe);
    float c[H];
#pragma unroll
    for (int h = 0; h < H; h++) c[h] = 0.f;
    const int* ep = epaths + idx * LMAX;
    for (int s = 0; s < npe; s++) {
        const float4* g = reinterpret_cast<const float4*>(
            dt + ((long)s * EE + ep[s]) * H);
        const float4 g0 = g[0], g1 = g[1];
        c[0] += g0.x; c[1] += g0.y; c[2] += g0.z; c[3] += g0.w;
        c[4] += g1.x; c[5] += g1.y; c[6] += g1.z; c[7] += g1.w;
    }
    const float inv = npe > 0 ? 1.f / (float)npe : 0.f;
    if (hsel < 0) {
#pragma unroll
        for (int h = 0; h < H; h++)
            scores[(long)h * NN * NN + idx] = bb + c[h] * inv;
    } else {
        scores[idx] = bb + c[hsel] * inv;
    }
}

__global__ void deg_k(const int* __restrict__ ei, int* __restrict__ ind,
                      int* __restrict__ outd)
{
    const int e = blockIdx.x * 256 + threadIdx.x;
    atomicAdd(&outd[ei[e]], 1);        // edge_index[0] = src
    atomicAdd(&ind[ei[EE + e]], 1);    // edge_index[1] = dst
}

__global__ void degembed_k(float* __restrict__ h, const int* __restrict__ ind,
                           const int* __restrict__ outd,
                           const float* __restrict__ z_in,
                           const float* __restrict__ z_out)
{
    const int idx = blockIdx.x * 256 + threadIdx.x;
    const int n = idx >> 8, c = idx & 255;
    int di = ind[n];  di = di > (MAXDEG - 1) ? (MAXDEG - 1) : di;
    int dw = outd[n]; dw = dw > (MAXDEG - 1) ? (MAXDEG - 1) : dw;
    h[idx] += z_in[di * ND + c] + z_out[dw * ND + c];
}

__global__ void sentinel_k(float* o) { o[0] = 12345.0f; }  // ws too small marker

// ---------------------------------------------------------------------------
extern "C" void kernel_launch(void* const* d_in, const int* in_sizes, int n_in,
                              void* d_out, int out_size, void* d_ws, size_t ws_size,
                              hipStream_t stream)
{
    const float* x      = (const float*)d_in[0];
    const int*   eidx   = (const int*)d_in[1];
    const float* eattr  = (const float*)d_in[2];
    const int*   ndist  = (const int*)d_in[3];
    const int*   epaths = (const int*)d_in[4];
    const float* Wn_in  = (const float*)d_in[5];
    const float* bn_in  = (const float*)d_in[6];
    const float* We_in  = (const float*)d_in[7];
    const float* be_in  = (const float*)d_in[8];
    const float* z_in   = (const float*)d_in[9];
    const float* z_out  = (const float*)d_in[10];
    const float* bspat  = (const float*)d_in[11];
    const float* ln1w   = (const float*)d_in[12];
    const float* ln1b   = (const float*)d_in[13];
    const float* ln2w   = (const float*)d_in[14];
    const float* ln2b   = (const float*)d_in[15];
    const float* Wq     = (const float*)d_in[16];
    const float* bq     = (const float*)d_in[17];
    const float* Wk     = (const float*)d_in[18];
    const float* bk     = (const float*)d_in[19];
    const float* Wv     = (const float*)d_in[20];
    const float* bv     = (const float*)d_in[21];
    const float* evec   = (const float*)d_in[22];
    const float* Wo     = (const float*)d_in[23];
    const float* bo     = (const float*)d_in[24];
    const float* Wff1   = (const float*)d_in[25];
    const float* bff1   = (const float*)d_in[26];
    const float* Wff2   = (const float*)d_in[27];
    const float* bff2   = (const float*)d_in[28];
    const float* Wout   = (const float*)d_in[29];
    const float* bout   = (const float*)d_in[30];
    float* out = (float*)d_out;

    // ---- workspace carve-up ----
    char* p = (char*)d_ws;
    auto alloc = [&](size_t bytes) -> char* {
        char* r = p;
        p += (bytes + 255) & ~(size_t)255;
        return r;
    };
    float* h    = (float*)alloc((size_t)NN * ND * 4);       //  2 MB
    float* xn   = (float*)alloc((size_t)NN * ND * 4);       //  2 MB
    float* e    = (float*)alloc((size_t)EE * ED * 4);       // 16 MB
    float* qb   = (float*)alloc((size_t)NN * H * ND * 4);   // 16 MB  [n][h*256+k]
    float* kb   = (float*)alloc((size_t)NN * H * ND * 4);   // 16 MB
    float* vb   = (float*)alloc((size_t)NN * H * ND * 4);   // 16 MB
    float* o2   = (float*)alloc((size_t)NN * H * ND * 4);   // 16 MB
    float* ff1  = (float*)alloc((size_t)NN * FF * 4);       //  8 MB
    float* dt   = (float*)alloc((size_t)LMAX * EE * H * 4); //  5 MB [s][e][h]
    int*   ind  = (int*)alloc(NN * 4);
    int*   outd = (int*)alloc(NN * 4);
    const size_t base_need = (size_t)(p - (char*)d_ws);
    const size_t sc_all = (size_t)H * NN * NN * 4;          // 134 MB
    const size_t sc_one = (size_t)NN * NN * 4;              // 16.8 MB
    bool allheads;
    float* scores;
    if (ws_size >= base_need + sc_all) {
        allheads = true;  scores = (float*)alloc(sc_all);
    } else if (ws_size >= base_need + sc_one) {
        allheads = false; scores = (float*)alloc(sc_one);
    } else {
        sentinel_k<<<1, 1, 0, stream>>>(out);
        return;
    }

    const float* nul = nullptr;
    const long NN2 = (long)NN * NN;

    // ---- degrees + input projections ----
    hipMemsetAsync(ind, 0, NN * 4, stream);
    hipMemsetAsync(outd, 0, NN * 4, stream);
    deg_k<<<EE / 256, 256, 0, stream>>>(eidx, ind, outd);

    gemm_k<64, 64, 4, 4, B_NORMAL, E_BIAS><<<dim3(ND / 64, NN / 64), 256, 0, stream>>>(
        x, IN_ND, 0, Wn_in, ND, 0, h, ND, 0, IN_ND, bn_in, 1.f);
    degembed_k<<<NN * ND / 256, 256, 0, stream>>>(h, ind, outd, z_in, z_out);

    gemm_k<64, 64, 4, 4, B_NORMAL, E_BIAS><<<dim3(ED / 64, EE / 64), 256, 0, stream>>>(
        eattr, IN_ED, 0, We_in, ED, 0, e, ED, 0, IN_ED, be_in, 1.f);

    const float scale = 1.f / 16.f;  // 1/sqrt(dk=256)

    for (int l = 0; l < NL; l++) {
        ln_k<<<NN / 4, 256, 0, stream>>>(h, ln1w + l * ND, ln1b + l * ND, xn);

        // Q/K/V: [2048,256] @ headpacked [256, 2048] -> [n][h*256+k]
        gemm_k<128, 128, 8, 8, B_HEADPACK, E_BIAS><<<dim3(H * ND / 128, NN / 128), 256, 0, stream>>>(
            xn, ND, 0, Wq + (size_t)l * H * ND * ND, 0, 0, qb, H * ND, 0, ND,
            bq + l * H * ND, 1.f);
        gemm_k<128, 128, 8, 8, B_HEADPACK, E_BIAS><<<dim3(H * ND / 128, NN / 128), 256, 0, stream>>>(
            xn, ND, 0, Wk + (size_t)l * H * ND * ND, 0, 0, kb, H * ND, 0, ND,
            bk + l * H * ND, 1.f);
        gemm_k<128, 128, 8, 8, B_HEADPACK, E_BIAS><<<dim3(H * ND / 128, NN / 128), 256, 0, stream>>>(
            xn, ND, 0, Wv + (size_t)l * H * ND * ND, 0, 0, vb, H * ND, 0, ND,
            bv + l * H * ND, 1.f);

        dotsT_k<<<dim3(EE / 256, LMAX), 256, 0, stream>>>(
            e, evec + (size_t)l * H * LMAX * ED, dt);

        if (allheads) {
            bias_k<<<(NN2 + 255) / 256, 256, 0, stream>>>(
                ndist, epaths, bspat, dt, scores, -1);
            gemm_k<128, 128, 8, 8, B_TRANS, E_ACC><<<dim3(NN / 128, NN / 128, H), 256, 0, stream>>>(
                qb, H * ND, ND, kb, H * ND, ND, scores, NN, NN2, ND,
                nul, scale);
            softmax_k<<<dim3(NN, 1, H), 256, 0, stream>>>(scores, NN2);
            gemm_k<128, 64, 8, 4, B_NORMAL, E_NONE><<<dim3(ND / 64, NN / 128, H), 256, 0, stream>>>(
                scores, NN, NN2, vb, H * ND, ND, o2, H * ND, ND, NN,
                nul, 1.f);
        } else {
            for (int hh = 0; hh < H; hh++) {
                bias_k<<<(NN2 + 255) / 256, 256, 0, stream>>>(
                    ndist, epaths, bspat, dt, scores, hh);
                gemm_k<128, 128, 8, 8, B_TRANS, E_ACC><<<dim3(NN / 128, NN / 128, 1), 256, 0, stream>>>(
                    qb + hh * ND, H * ND, 0, kb + hh * ND, H * ND, 0, scores, NN, 0, ND,
                    nul, scale);
                softmax_k<<<dim3(NN, 1, 1), 256, 0, stream>>>(scores, 0);
                gemm_k<128, 64, 8, 4, B_NORMAL, E_NONE><<<dim3(ND / 64, NN / 128, 1), 256, 0, stream>>>(
                    scores, NN, 0, vb + hh * ND, H * ND, 0, o2 + hh * ND, H * ND, 0, NN,
                    nul, 1.f);
            }
        }

        // h = o2 @ Wo[l] + bo[l] + h
        gemm_k<64, 64, 4, 4, B_NORMAL, E_BIAS_RES><<<dim3(ND / 64, NN / 64), 256, 0, stream>>>(
            o2, H * ND, 0, Wo + (size_t)l * H * ND * ND, ND, 0, h, ND, 0, H * ND,
            bo + l * ND, 1.f);

        ln_k<<<NN / 4, 256, 0, stream>>>(h, ln2w + l * ND, ln2b + l * ND, xn);

        gemm_k<128, 128, 8, 8, B_NORMAL, E_BIAS_GELU><<<dim3(FF / 128, NN / 128), 256, 0, stream>>>(
            xn, ND, 0, Wff1 + (size_t)l * ND * FF, FF, 0, ff1, FF, 0, ND,
            bff1 + l * FF, 1.f);
        gemm_k<64, 64, 4, 4, B_NORMAL, E_BIAS_RES><<<dim3(ND / 64, NN / 64), 256, 0, stream>>>(
            ff1, FF, 0, Wff2 + (size_t)l * FF * ND, ND, 0, h, ND, 0, FF,
            bff2 + l * ND, 1.f);
    }

    gemm_k<64, 64, 4, 4, B_NORMAL, E_BIAS><<<dim3(ND / 64, NN / 64), 256, 0, stream>>>(
        h, ND, 0, Wout, ND, 0, out, ND, 0, ND, bout, 1.f);
}

// Round 3
// 1253.361 us; speedup vs baseline: 4.5191x; 2.9607x over previous
//
#include <hip/hip_runtime.h>

// ---------------------------------------------------------------------------
// Graphormer forward, MI355X. Round 2: all GEMMs -> bf16 MFMA
// (v_mfma_f32_16x16x32_bf16), 128x128 tile, BK=32, 4 waves (2x2), swizzled
// LDS (slot ^= (row>>1)&3 -> conflict-free b128 reads), f32 accum, fused
// epilogues. Weights converted+transposed to bf16 [ncol][K] once per launch.
// Scores kept bf16 end-to-end: bias_k writes bias, QK^T accumulates, softmax
// in place, PV consumes.
// ---------------------------------------------------------------------------

constexpr int NN    = 2048;   // nodes
constexpr int EE    = 32768;  // edges
constexpr int IN_ND = 128;
constexpr int ND    = 256;
constexpr int IN_ED = 64;
constexpr int ED    = 128;
constexpr int H     = 8;
constexpr int FF    = 1024;
constexpr int NL    = 3;
constexpr int LMAX  = 5;
constexpr int MAXDEG= 64;

enum { E_NONE = 0, E_BIAS = 1, E_BIAS_RES = 2, E_BIAS_GELU = 3, E_ACC = 4 };

using u16 = unsigned short;
using short8 = __attribute__((ext_vector_type(8))) short;   // 8 bf16 (4 VGPR)
using f32x4  = __attribute__((ext_vector_type(4))) float;

__device__ __forceinline__ u16 f2bf(float f) {              // RNE f32->bf16
    unsigned u = __float_as_uint(f);
    u += 0x7fff + ((u >> 16) & 1);
    return (u16)(u >> 16);
}
__device__ __forceinline__ float bf2f(u16 h) {
    return __uint_as_float((unsigned)h << 16);
}
__device__ __forceinline__ float gelu_f(float x) {
    return 0.5f * x * (1.0f + erff(x * 0.70710678118654752440f));
}

// ---------------------------------------------------------------------------
// bf16 MFMA GEMM: C[row,col] = epi( sum_k A[row,k] * B[col,k] )  (B^T layout)
// 128x128 tile, BK=32. 256 thr = 4 waves, wave (wr,wc) owns 64x64 quadrant.
// LDS swizzle: 16B slot' = slot ^ ((row>>1)&3)  (rows 0..7 sweep all banks).
// OBF: write bf16 (else f32). E_ACC reads+writes bf16 C (scores).
// ---------------------------------------------------------------------------
template<int EPI, int OBF>
__global__ __launch_bounds__(256)
void mgemm_k(const u16* __restrict__ A, int lda, long aZs,
             const u16* __restrict__ B, int ldb, long bZs,
             void* __restrict__ Cp, int ldc, long cZs,
             int K, const float* __restrict__ bias, float scale)
{
    const int z = blockIdx.z;
    A += (long)z * aZs;
    B += (long)z * bZs;
    const int row0 = blockIdx.y * 128, col0 = blockIdx.x * 128;
    const int tid = threadIdx.x;
    const int lane = tid & 63, wv = tid >> 6;
    const int wr = wv >> 1, wc = wv & 1;
    const int fl = lane & 15, kg = lane >> 4;

    __shared__ u16 As[128 * 32];
    __shared__ u16 Bs[128 * 32];

    // fragment read byte-offsets (constant over K loop)
    int aoff[4], boff[4];
#pragma unroll
    for (int m = 0; m < 4; m++) {
        int r = wr * 64 + m * 16 + fl;
        aoff[m] = r * 64 + ((kg ^ ((r >> 1) & 3)) * 16);
        r = wc * 64 + m * 16 + fl;
        boff[m] = r * 64 + ((kg ^ ((r >> 1) & 3)) * 16);
    }

    // staging: 512 chunks of 16B per tile; thread t owns chunks 2t, 2t+1
    const int id0 = tid * 2, id1 = id0 + 1;
    const int sr0 = id0 >> 2, sl0 = id0 & 3;
    const int sr1 = id1 >> 2, sl1 = id1 & 3;
    const int wb0 = sr0 * 64 + ((sl0 ^ ((sr0 >> 1) & 3)) * 16);
    const int wb1 = sr1 * 64 + ((sl1 ^ ((sr1 >> 1) & 3)) * 16);
    const u16* ga0 = A + (long)(row0 + sr0) * lda + sl0 * 8;
    const u16* ga1 = A + (long)(row0 + sr1) * lda + sl1 * 8;
    const u16* gb0 = B + (long)(col0 + sr0) * ldb + sl0 * 8;
    const u16* gb1 = B + (long)(col0 + sr1) * ldb + sl1 * 8;

    const f32x4 zero = {0.f, 0.f, 0.f, 0.f};
    f32x4 acc[4][4];
#pragma unroll
    for (int m = 0; m < 4; m++)
#pragma unroll
        for (int n = 0; n < 4; n++) acc[m][n] = zero;

    for (int k0 = 0; k0 < K; k0 += 32) {
        const uint4 va0 = *(const uint4*)(ga0 + k0);
        const uint4 va1 = *(const uint4*)(ga1 + k0);
        const uint4 vb0 = *(const uint4*)(gb0 + k0);
        const uint4 vb1 = *(const uint4*)(gb1 + k0);
        __syncthreads();                       // prev iter's reads done
        *(uint4*)((char*)As + wb0) = va0;
        *(uint4*)((char*)As + wb1) = va1;
        *(uint4*)((char*)Bs + wb0) = vb0;
        *(uint4*)((char*)Bs + wb1) = vb1;
        __syncthreads();
        short8 af[4], bfr[4];
#pragma unroll
        for (int m = 0; m < 4; m++)
            af[m] = *(const short8*)((const char*)As + aoff[m]);
#pragma unroll
        for (int n = 0; n < 4; n++)
            bfr[n] = *(const short8*)((const char*)Bs + boff[n]);
#pragma unroll
        for (int m = 0; m < 4; m++)
#pragma unroll
            for (int n = 0; n < 4; n++)
                acc[m][n] = __builtin_amdgcn_mfma_f32_16x16x32_bf16(
                    af[m], bfr[n], acc[m][n], 0, 0, 0);
    }

    float* Cf = (float*)Cp + (long)z * cZs;
    u16*   Cb = (u16*)Cp   + (long)z * cZs;
#pragma unroll
    for (int n = 0; n < 4; n++) {
        const int col = col0 + wc * 64 + n * 16 + fl;
        float bcol = 0.f;
        if constexpr (EPI == E_BIAS || EPI == E_BIAS_RES || EPI == E_BIAS_GELU)
            bcol = bias[col];
#pragma unroll
        for (int m = 0; m < 4; m++) {
            const f32x4 v = acc[m][n];
#pragma unroll
            for (int r = 0; r < 4; r++) {
                const int row = row0 + wr * 64 + m * 16 + kg * 4 + r;
                float x = v[r];
                if constexpr (EPI == E_BIAS)       x += bcol;
                else if constexpr (EPI == E_BIAS_RES)  x += bcol + Cf[(long)row * ldc + col];
                else if constexpr (EPI == E_BIAS_GELU) x = gelu_f(x + bcol);
                else if constexpr (EPI == E_ACC)       x = x * scale + bf2f(Cb[(long)row * ldc + col]);
                if constexpr (OBF) Cb[(long)row * ldc + col] = f2bf(x);
                else               Cf[(long)row * ldc + col] = x;
            }
        }
    }
}

// ---------------------------------------------------------------------------
// Tiled transpose + (optional) f32->bf16 convert: out[c][r] = in[r][c].
// 64x64 tiles, 256 threads. R, C multiples of 64.
// ---------------------------------------------------------------------------
template<int INF32>
__global__ __launch_bounds__(256)
void transp_k(const void* __restrict__ inp, long inZs,
              u16* __restrict__ out, long outZs, int R, int C)
{
    const int z = blockIdx.z;
    const int r0 = blockIdx.y * 64, c0 = blockIdx.x * 64;
    __shared__ u16 t[64][68];
    const int tx = threadIdx.x & 63, ty = threadIdx.x >> 6;
    if constexpr (INF32) {
        const float* in = (const float*)inp + (long)z * inZs;
#pragma unroll
        for (int i = 0; i < 16; i++) {
            const int r = i * 4 + ty;
            t[r][tx] = f2bf(in[(long)(r0 + r) * C + c0 + tx]);
        }
    } else {
        const u16* in = (const u16*)inp + (long)z * inZs;
#pragma unroll
        for (int i = 0; i < 16; i++) {
            const int r = i * 4 + ty;
            t[r][tx] = in[(long)(r0 + r) * C + c0 + tx];
        }
    }
    __syncthreads();
    u16* o = out + (long)z * outZs;
#pragma unroll
    for (int i = 0; i < 16; i++) {
        const int r = i * 4 + ty;
        o[(long)(c0 + r) * R + r0 + tx] = t[tx][r];
    }
}

// elementwise f32 -> bf16 (size multiple of 1024)
__global__ __launch_bounds__(256)
void cvt_k(const float* __restrict__ in, u16* __restrict__ out)
{
    const long i = (long)blockIdx.x * 256 + threadIdx.x;
    const float4 v = ((const float4*)in)[i];
    ushort4 o;
    o.x = f2bf(v.x); o.y = f2bf(v.y); o.z = f2bf(v.z); o.w = f2bf(v.w);
    ((ushort4*)out)[i] = o;
}

// ---------------------------------------------------------------------------
// LayerNorm rows of ND=256, f32 in -> bf16 out. One wave per row.
// ---------------------------------------------------------------------------
__global__ __launch_bounds__(256)
void ln_k(const float* __restrict__ x, const float* __restrict__ w,
          const float* __restrict__ b, u16* __restrict__ y)
{
    const int wid = threadIdx.x >> 6, lane = threadIdx.x & 63;
    const int row = blockIdx.x * 4 + wid;
    const float4 v = reinterpret_cast<const float4*>(x + (long)row * ND)[lane];
    float s = v.x + v.y + v.z + v.w;
#pragma unroll
    for (int o = 32; o >= 1; o >>= 1) s += __shfl_xor(s, o);
    const float mean = s * (1.f / ND);
    const float d0 = v.x - mean, d1 = v.y - mean, d2 = v.z - mean, d3 = v.w - mean;
    float sq = d0 * d0 + d1 * d1 + d2 * d2 + d3 * d3;
#pragma unroll
    for (int o = 32; o >= 1; o >>= 1) sq += __shfl_xor(sq, o);
    const float rstd = rsqrtf(sq * (1.f / ND) + 1e-5f);
    const float4 wv = reinterpret_cast<const float4*>(w)[lane];
    const float4 bv = reinterpret_cast<const float4*>(b)[lane];
    ushort4 o4;
    o4.x = f2bf(d0 * rstd * wv.x + bv.x);
    o4.y = f2bf(d1 * rstd * wv.y + bv.y);
    o4.z = f2bf(d2 * rstd * wv.z + bv.z);
    o4.w = f2bf(d3 * rstd * wv.w + bv.w);
    reinterpret_cast<ushort4*>(y + (long)row * ND)[lane] = o4;
}

// ---------------------------------------------------------------------------
// Row softmax, bf16 in place, f32 internal. grid (NN, 1, H).
// ---------------------------------------------------------------------------
__global__ __launch_bounds__(256)
void softmax_k(u16* __restrict__ sc, long zstride)
{
    u16* r = sc + (long)blockIdx.z * zstride + (long)blockIdx.x * NN;
    const int t = threadIdx.x;
    uint4 u = ((uint4*)r)[t];
    float f[8];
    f[0] = bf2f(u.x & 0xffff); f[1] = bf2f(u.x >> 16);
    f[2] = bf2f(u.y & 0xffff); f[3] = bf2f(u.y >> 16);
    f[4] = bf2f(u.z & 0xffff); f[5] = bf2f(u.z >> 16);
    f[6] = bf2f(u.w & 0xffff); f[7] = bf2f(u.w >> 16);
    float m = f[0];
#pragma unroll
    for (int i = 1; i < 8; i++) m = fmaxf(m, f[i]);
    __shared__ float red[4];
#pragma unroll
    for (int o = 32; o >= 1; o >>= 1) m = fmaxf(m, __shfl_xor(m, o));
    if ((t & 63) == 0) red[t >> 6] = m;
    __syncthreads();
    m = fmaxf(fmaxf(red[0], red[1]), fmaxf(red[2], red[3]));
    __syncthreads();
    float s = 0.f;
#pragma unroll
    for (int i = 0; i < 8; i++) { f[i] = expf(f[i] - m); s += f[i]; }
#pragma unroll
    for (int o = 32; o >= 1; o >>= 1) s += __shfl_xor(s, o);
    if ((t & 63) == 0) red[t >> 6] = s;
    __syncthreads();
    s = red[0] + red[1] + red[2] + red[3];
    const float inv = 1.f / s;
    uint4 w;
    w.x = (unsigned)f2bf(f[0] * inv) | ((unsigned)f2bf(f[1] * inv) << 16);
    w.y = (unsigned)f2bf(f[2] * inv) | ((unsigned)f2bf(f[3] * inv) << 16);
    w.z = (unsigned)f2bf(f[4] * inv) | ((unsigned)f2bf(f[5] * inv) << 16);
    w.w = (unsigned)f2bf(f[6] * inv) | ((unsigned)f2bf(f[7] * inv) << 16);
    ((uint4*)r)[t] = w;
}

// ---------------------------------------------------------------------------
// Edge-dot precompute: dt[s][e][h] = evec_l[h,s,:] . e[e,:]   (e is bf16)
// grid (EE/256, LMAX)
// ---------------------------------------------------------------------------
__global__ __launch_bounds__(256)
void dotsT_k(const u16* __restrict__ e, const float* __restrict__ evl,
             float* __restrict__ dt)
{
    const int s = blockIdx.y;
    const int ei = blockIdx.x * 256 + threadIdx.x;
    __shared__ float evs[H * ED];
    for (int i = threadIdx.x; i < H * ED; i += 256)
        evs[i] = evl[((i >> 7) * LMAX + s) * ED + (i & 127)];
    __syncthreads();
    const uint4* er = (const uint4*)(e + (long)ei * ED);
    float c[H];
#pragma unroll
    for (int h = 0; h < H; h++) c[h] = 0.f;
#pragma unroll
    for (int d8 = 0; d8 < ED / 8; d8++) {
        const uint4 q = er[d8];
        float f[8];
        f[0] = bf2f(q.x & 0xffff); f[1] = bf2f(q.x >> 16);
        f[2] = bf2f(q.y & 0xffff); f[3] = bf2f(q.y >> 16);
        f[4] = bf2f(q.z & 0xffff); f[5] = bf2f(q.z >> 16);
        f[6] = bf2f(q.w & 0xffff); f[7] = bf2f(q.w >> 16);
#pragma unroll
        for (int h = 0; h < H; h++) {
            const float* w = &evs[h * ED + d8 * 8];
            float a = w[0] * f[0] + w[1] * f[1] + w[2] * f[2] + w[3] * f[3]
                    + w[4] * f[4] + w[5] * f[5] + w[6] * f[6] + w[7] * f[7];
            c[h] += a;
        }
    }
    float4* o = reinterpret_cast<float4*>(dt + ((long)s * EE + ei) * H);
    o[0] = make_float4(c[0], c[1], c[2], c[3]);
    o[1] = make_float4(c[4], c[5], c[6], c[7]);
}

// ---------------------------------------------------------------------------
// Attention bias -> bf16 scores init: sc[h][n][m] = b_mat + c[h]
// ---------------------------------------------------------------------------
__global__ __launch_bounds__(256)
void bias_k(const int* __restrict__ ndist, const int* __restrict__ epaths,
            const float* __restrict__ bspat, const float* __restrict__ dt,
            u16* __restrict__ sc)
{
    const long idx = (long)blockIdx.x * 256 + threadIdx.x;
    const int d = ndist[idx];
    float bb = 0.f;
    if (d > 0) bb = bspat[(d < LMAX ? d : LMAX) - 1];
    int npe = d - 1;
    npe = npe < 0 ? 0 : (npe > LMAX ? LMAX : npe);
    float c[H];
#pragma unroll
    for (int h = 0; h < H; h++) c[h] = 0.f;
    const int* ep = epaths + idx * LMAX;
    for (int s = 0; s < npe; s++) {
        const float4* g = reinterpret_cast<const float4*>(
            dt + ((long)s * EE + ep[s]) * H);
        const float4 g0 = g[0], g1 = g[1];
        c[0] += g0.x; c[1] += g0.y; c[2] += g0.z; c[3] += g0.w;
        c[4] += g1.x; c[5] += g1.y; c[6] += g1.z; c[7] += g1.w;
    }
    const float inv = npe > 0 ? 1.f / (float)npe : 0.f;
    const long NN2 = (long)NN * NN;
#pragma unroll
    for (int h = 0; h < H; h++)
        sc[(long)h * NN2 + idx] = f2bf(bb + c[h] * inv);
}

__global__ void deg_k(const int* __restrict__ ei, int* __restrict__ ind,
                      int* __restrict__ outd)
{
    const int e = blockIdx.x * 256 + threadIdx.x;
    atomicAdd(&outd[ei[e]], 1);        // edge_index[0] = src
    atomicAdd(&ind[ei[EE + e]], 1);    // edge_index[1] = dst
}

__global__ void degembed_k(float* __restrict__ h, const int* __restrict__ ind,
                           const int* __restrict__ outd,
                           const float* __restrict__ z_in,
                           const float* __restrict__ z_out)
{
    const int idx = blockIdx.x * 256 + threadIdx.x;
    const int n = idx >> 8, c = idx & 255;
    int di = ind[n];  di = di > (MAXDEG - 1) ? (MAXDEG - 1) : di;
    int dw = outd[n]; dw = dw > (MAXDEG - 1) ? (MAXDEG - 1) : dw;
    h[idx] += z_in[di * ND + c] + z_out[dw * ND + c];
}

__global__ void sentinel_k(float* o) { o[0] = 12345.0f; }  // ws too small marker

// ---------------------------------------------------------------------------
extern "C" void kernel_launch(void* const* d_in, const int* in_sizes, int n_in,
                              void* d_out, int out_size, void* d_ws, size_t ws_size,
                              hipStream_t stream)
{
    const float* x      = (const float*)d_in[0];
    const int*   eidx   = (const int*)d_in[1];
    const float* eattr  = (const float*)d_in[2];
    const int*   ndist  = (const int*)d_in[3];
    const int*   epaths = (const int*)d_in[4];
    const float* Wn_in  = (const float*)d_in[5];
    const float* bn_in  = (const float*)d_in[6];
    const float* We_in  = (const float*)d_in[7];
    const float* be_in  = (const float*)d_in[8];
    const float* z_in   = (const float*)d_in[9];
    const float* z_out  = (const float*)d_in[10];
    const float* bspat  = (const float*)d_in[11];
    const float* ln1w   = (const float*)d_in[12];
    const float* ln1b   = (const float*)d_in[13];
    const float* ln2w   = (const float*)d_in[14];
    const float* ln2b   = (const float*)d_in[15];
    const float* Wq     = (const float*)d_in[16];
    const float* bq     = (const float*)d_in[17];
    const float* Wk     = (const float*)d_in[18];
    const float* bk     = (const float*)d_in[19];
    const float* Wv     = (const float*)d_in[20];
    const float* bv     = (const float*)d_in[21];
    const float* evec   = (const float*)d_in[22];
    const float* Wo     = (const float*)d_in[23];
    const float* bo     = (const float*)d_in[24];
    const float* Wff1   = (const float*)d_in[25];
    const float* bff1   = (const float*)d_in[26];
    const float* Wff2   = (const float*)d_in[27];
    const float* bff2   = (const float*)d_in[28];
    const float* Wout   = (const float*)d_in[29];
    const float* bout   = (const float*)d_in[30];
    float* out = (float*)d_out;

    // ---- workspace carve-up ----
    char* p = (char*)d_ws;
    auto alloc = [&](size_t bytes) -> char* {
        char* r = p;
        p += (bytes + 255) & ~(size_t)255;
        return r;
    };
    float* h    = (float*)alloc((size_t)NN * ND * 4);         // f32 activations
    u16*   hb   = (u16*)alloc((size_t)NN * ND * 2);
    u16*   xb   = (u16*)alloc((size_t)NN * IN_ND * 2);
    u16*   xnb  = (u16*)alloc((size_t)NN * ND * 2);
    u16*   eb   = (u16*)alloc((size_t)EE * IN_ED * 2);
    u16*   e_bf = (u16*)alloc((size_t)EE * ED * 2);
    u16*   qb   = (u16*)alloc((size_t)NN * H * ND * 2);
    u16*   kb   = (u16*)alloc((size_t)NN * H * ND * 2);
    u16*   vb   = (u16*)alloc((size_t)NN * H * ND * 2);
    u16*   vT   = (u16*)alloc((size_t)NN * H * ND * 2);       // [h*256+d][m]
    u16*   o2   = (u16*)alloc((size_t)NN * H * ND * 2);
    u16*   ff1b = (u16*)alloc((size_t)NN * FF * 2);
    float* dt   = (float*)alloc((size_t)LMAX * EE * H * 4);   // [s][e][h] f32
    u16*   WqT  = (u16*)alloc((size_t)NL * H * ND * ND * 2);  // [l][h*256+o][d]
    u16*   WkT  = (u16*)alloc((size_t)NL * H * ND * ND * 2);
    u16*   WvT  = (u16*)alloc((size_t)NL * H * ND * ND * 2);
    u16*   WoT  = (u16*)alloc((size_t)NL * ND * H * ND * 2);  // [l][256][2048]
    u16*   W1T  = (u16*)alloc((size_t)NL * FF * ND * 2);      // [l][1024][256]
    u16*   W2T  = (u16*)alloc((size_t)NL * ND * FF * 2);      // [l][256][1024]
    u16*   WnT  = (u16*)alloc((size_t)ND * IN_ND * 2);
    u16*   WeT  = (u16*)alloc((size_t)ED * IN_ED * 2);
    u16*   WouT = (u16*)alloc((size_t)ND * ND * 2);
    int*   ind  = (int*)alloc(NN * 4);
    int*   outd = (int*)alloc(NN * 4);
    u16*   sc   = (u16*)alloc((size_t)H * NN * NN * 2);       // 67 MB bf16
    if ((size_t)(p - (char*)d_ws) > ws_size) {
        sentinel_k<<<1, 1, 0, stream>>>(out);
        return;
    }

    const long NN2 = (long)NN * NN;
    const float* nul = nullptr;

    // ---- degrees ----
    hipMemsetAsync(ind, 0, NN * 4, stream);
    hipMemsetAsync(outd, 0, NN * 4, stream);
    deg_k<<<EE / 256, 256, 0, stream>>>(eidx, ind, outd);

    // ---- input converts + weight transposes (bf16) ----
    cvt_k<<<NN * IN_ND / 1024, 256, 0, stream>>>(x, xb);
    cvt_k<<<EE * IN_ED / 1024, 256, 0, stream>>>(eattr, eb);
    transp_k<1><<<dim3(4, 4, NL * H), 256, 0, stream>>>(Wq, ND * ND, WqT, ND * ND, ND, ND);
    transp_k<1><<<dim3(4, 4, NL * H), 256, 0, stream>>>(Wk, ND * ND, WkT, ND * ND, ND, ND);
    transp_k<1><<<dim3(4, 4, NL * H), 256, 0, stream>>>(Wv, ND * ND, WvT, ND * ND, ND, ND);
    transp_k<1><<<dim3(4, 32, NL), 256, 0, stream>>>(Wo, (long)H * ND * ND, WoT, (long)H * ND * ND, H * ND, ND);
    transp_k<1><<<dim3(16, 4, NL), 256, 0, stream>>>(Wff1, (long)ND * FF, W1T, (long)ND * FF, ND, FF);
    transp_k<1><<<dim3(4, 16, NL), 256, 0, stream>>>(Wff2, (long)ND * FF, W2T, (long)ND * FF, FF, ND);
    transp_k<1><<<dim3(4, 2, 1), 256, 0, stream>>>(Wn_in, 0, WnT, 0, IN_ND, ND);
    transp_k<1><<<dim3(2, 1, 1), 256, 0, stream>>>(We_in, 0, WeT, 0, IN_ED, ED);
    transp_k<1><<<dim3(4, 4, 1), 256, 0, stream>>>(Wout, 0, WouT, 0, ND, ND);

    // ---- input projections ----
    mgemm_k<E_BIAS, 0><<<dim3(2, 16), 256, 0, stream>>>(
        xb, IN_ND, 0, WnT, IN_ND, 0, h, ND, 0, IN_ND, bn_in, 1.f);
    degembed_k<<<NN * ND / 256, 256, 0, stream>>>(h, ind, outd, z_in, z_out);
    mgemm_k<E_BIAS, 1><<<dim3(1, EE / 128), 256, 0, stream>>>(
        eb, IN_ED, 0, WeT, IN_ED, 0, e_bf, ED, 0, IN_ED, be_in, 1.f);

    const float scale = 1.f / 16.f;  // 1/sqrt(dk=256)

    for (int l = 0; l < NL; l++) {
        ln_k<<<NN / 4, 256, 0, stream>>>(h, ln1w + l * ND, ln1b + l * ND, xnb);

        mgemm_k<E_BIAS, 1><<<dim3(16, 16), 256, 0, stream>>>(
            xnb, ND, 0, WqT + (size_t)l * H * ND * ND, ND, 0,
            qb, H * ND, 0, ND, bq + l * H * ND, 1.f);
        mgemm_k<E_BIAS, 1><<<dim3(16, 16), 256, 0, stream>>>(
            xnb, ND, 0, WkT + (size_t)l * H * ND * ND, ND, 0,
            kb, H * ND, 0, ND, bk + l * H * ND, 1.f);
        mgemm_k<E_BIAS, 1><<<dim3(16, 16), 256, 0, stream>>>(
            xnb, ND, 0, WvT + (size_t)l * H * ND * ND, ND, 0,
            vb, H * ND, 0, ND, bv + l * H * ND, 1.f);
        transp_k<0><<<dim3(32, 32, 1), 256, 0, stream>>>(
            vb, 0, vT, 0, NN, H * ND);

        dotsT_k<<<dim3(EE / 256, LMAX), 256, 0, stream>>>(
            e_bf, evec + (size_t)l * H * LMAX * ED, dt);
        bias_k<<<(int)(NN2 / 256), 256, 0, stream>>>(ndist, epaths, bspat, dt, sc);

        // QK^T accumulating onto bias (bf16 C)
        mgemm_k<E_ACC, 1><<<dim3(16, 16, H), 256, 0, stream>>>(
            qb, H * ND, ND, kb, H * ND, ND, sc, NN, NN2, ND, nul, scale);
        softmax_k<<<dim3(NN, 1, H), 256, 0, stream>>>(sc, NN2);
        // PV: A = probs (bf16), B = vT
        mgemm_k<E_NONE, 1><<<dim3(2, 16, H), 256, 0, stream>>>(
            sc, NN, NN2, vT, NN, (long)ND * NN, o2, H * ND, ND, NN, nul, 1.f);

        // h = o2 @ Wo + bo + h
        mgemm_k<E_BIAS_RES, 0><<<dim3(2, 16), 256, 0, stream>>>(
            o2, H * ND, 0, WoT + (size_t)l * ND * H * ND, H * ND, 0,
            h, ND, 0, H * ND, bo + l * ND, 1.f);

        ln_k<<<NN / 4, 256, 0, stream>>>(h, ln2w + l * ND, ln2b + l * ND, xnb);
        mgemm_k<E_BIAS_GELU, 1><<<dim3(8, 16), 256, 0, stream>>>(
            xnb, ND, 0, W1T + (size_t)l * FF * ND, ND, 0,
            ff1b, FF, 0, ND, bff1 + l * FF, 1.f);
        mgemm_k<E_BIAS_RES, 0><<<dim3(2, 16), 256, 0, stream>>>(
            ff1b, FF, 0, W2T + (size_t)l * ND * FF, FF, 0,
            h, ND, 0, FF, bff2 + l * ND, 1.f);
    }

    cvt_k<<<NN * ND / 1024, 256, 0, stream>>>(h, hb);
    mgemm_k<E_BIAS, 0><<<dim3(2, 16), 256, 0, stream>>>(
        hb, ND, 0, WouT, ND, 0, out, ND, 0, ND, bout, 1.f);
}

// Round 4
// 1163.122 us; speedup vs baseline: 4.8697x; 1.0776x over previous
//
#include <hip/hip_runtime.h>

// ---------------------------------------------------------------------------
// Graphormer forward, MI355X. Round 3: bias path compaction.
//  - pack_k: ndist+epaths -> 3 SoA u32 arrays (12B/pair, 50 MB, L3-resident)
//  - bias_k: predicated unrolled gathers (ILP), dt in bf16 (one 16B gather
//    serves all 8 heads per path step)
// GEMMs remain bf16 MFMA 128x128/BK32 from round 2.
// ---------------------------------------------------------------------------

constexpr int NN    = 2048;   // nodes
constexpr int EE    = 32768;  // edges
constexpr int IN_ND = 128;
constexpr int ND    = 256;
constexpr int IN_ED = 64;
constexpr int ED    = 128;
constexpr int H     = 8;
constexpr int FF    = 1024;
constexpr int NL    = 3;
constexpr int LMAX  = 5;
constexpr int MAXDEG= 64;

enum { E_NONE = 0, E_BIAS = 1, E_BIAS_RES = 2, E_BIAS_GELU = 3, E_ACC = 4 };

using u16 = unsigned short;
using short8 = __attribute__((ext_vector_type(8))) short;   // 8 bf16 (4 VGPR)
using f32x4  = __attribute__((ext_vector_type(4))) float;

__device__ __forceinline__ u16 f2bf(float f) {              // RNE f32->bf16
    unsigned u = __float_as_uint(f);
    u += 0x7fff + ((u >> 16) & 1);
    return (u16)(u >> 16);
}
__device__ __forceinline__ float bf2f(u16 h) {
    return __uint_as_float((unsigned)h << 16);
}
__device__ __forceinline__ float gelu_f(float x) {
    return 0.5f * x * (1.0f + erff(x * 0.70710678118654752440f));
}

// ---------------------------------------------------------------------------
// bf16 MFMA GEMM: C[row,col] = epi( sum_k A[row,k] * B[col,k] )  (B^T layout)
// 128x128 tile, BK=32. 256 thr = 4 waves, wave (wr,wc) owns 64x64 quadrant.
// ---------------------------------------------------------------------------
template<int EPI, int OBF>
__global__ __launch_bounds__(256)
void mgemm_k(const u16* __restrict__ A, int lda, long aZs,
             const u16* __restrict__ B, int ldb, long bZs,
             void* __restrict__ Cp, int ldc, long cZs,
             int K, const float* __restrict__ bias, float scale)
{
    const int z = blockIdx.z;
    A += (long)z * aZs;
    B += (long)z * bZs;
    const int row0 = blockIdx.y * 128, col0 = blockIdx.x * 128;
    const int tid = threadIdx.x;
    const int lane = tid & 63, wv = tid >> 6;
    const int wr = wv >> 1, wc = wv & 1;
    const int fl = lane & 15, kg = lane >> 4;

    __shared__ u16 As[128 * 32];
    __shared__ u16 Bs[128 * 32];

    int aoff[4], boff[4];
#pragma unroll
    for (int m = 0; m < 4; m++) {
        int r = wr * 64 + m * 16 + fl;
        aoff[m] = r * 64 + ((kg ^ ((r >> 1) & 3)) * 16);
        r = wc * 64 + m * 16 + fl;
        boff[m] = r * 64 + ((kg ^ ((r >> 1) & 3)) * 16);
    }

    const int id0 = tid * 2, id1 = id0 + 1;
    const int sr0 = id0 >> 2, sl0 = id0 & 3;
    const int sr1 = id1 >> 2, sl1 = id1 & 3;
    const int wb0 = sr0 * 64 + ((sl0 ^ ((sr0 >> 1) & 3)) * 16);
    const int wb1 = sr1 * 64 + ((sl1 ^ ((sr1 >> 1) & 3)) * 16);
    const u16* ga0 = A + (long)(row0 + sr0) * lda + sl0 * 8;
    const u16* ga1 = A + (long)(row0 + sr1) * lda + sl1 * 8;
    const u16* gb0 = B + (long)(col0 + sr0) * ldb + sl0 * 8;
    const u16* gb1 = B + (long)(col0 + sr1) * ldb + sl1 * 8;

    const f32x4 zero = {0.f, 0.f, 0.f, 0.f};
    f32x4 acc[4][4];
#pragma unroll
    for (int m = 0; m < 4; m++)
#pragma unroll
        for (int n = 0; n < 4; n++) acc[m][n] = zero;

    for (int k0 = 0; k0 < K; k0 += 32) {
        const uint4 va0 = *(const uint4*)(ga0 + k0);
        const uint4 va1 = *(const uint4*)(ga1 + k0);
        const uint4 vb0 = *(const uint4*)(gb0 + k0);
        const uint4 vb1 = *(const uint4*)(gb1 + k0);
        __syncthreads();
        *(uint4*)((char*)As + wb0) = va0;
        *(uint4*)((char*)As + wb1) = va1;
        *(uint4*)((char*)Bs + wb0) = vb0;
        *(uint4*)((char*)Bs + wb1) = vb1;
        __syncthreads();
        short8 af[4], bfr[4];
#pragma unroll
        for (int m = 0; m < 4; m++)
            af[m] = *(const short8*)((const char*)As + aoff[m]);
#pragma unroll
        for (int n = 0; n < 4; n++)
            bfr[n] = *(const short8*)((const char*)Bs + boff[n]);
#pragma unroll
        for (int m = 0; m < 4; m++)
#pragma unroll
            for (int n = 0; n < 4; n++)
                acc[m][n] = __builtin_amdgcn_mfma_f32_16x16x32_bf16(
                    af[m], bfr[n], acc[m][n], 0, 0, 0);
    }

    float* Cf = (float*)Cp + (long)z * cZs;
    u16*   Cb = (u16*)Cp   + (long)z * cZs;
#pragma unroll
    for (int n = 0; n < 4; n++) {
        const int col = col0 + wc * 64 + n * 16 + fl;
        float bcol = 0.f;
        if constexpr (EPI == E_BIAS || EPI == E_BIAS_RES || EPI == E_BIAS_GELU)
            bcol = bias[col];
#pragma unroll
        for (int m = 0; m < 4; m++) {
            const f32x4 v = acc[m][n];
#pragma unroll
            for (int r = 0; r < 4; r++) {
                const int row = row0 + wr * 64 + m * 16 + kg * 4 + r;
                float x = v[r];
                if constexpr (EPI == E_BIAS)       x += bcol;
                else if constexpr (EPI == E_BIAS_RES)  x += bcol + Cf[(long)row * ldc + col];
                else if constexpr (EPI == E_BIAS_GELU) x = gelu_f(x + bcol);
                else if constexpr (EPI == E_ACC)       x = x * scale + bf2f(Cb[(long)row * ldc + col]);
                if constexpr (OBF) Cb[(long)row * ldc + col] = f2bf(x);
                else               Cf[(long)row * ldc + col] = x;
            }
        }
    }
}

// ---------------------------------------------------------------------------
// Tiled transpose + (optional) f32->bf16 convert: out[c][r] = in[r][c].
// ---------------------------------------------------------------------------
template<int INF32>
__global__ __launch_bounds__(256)
void transp_k(const void* __restrict__ inp, long inZs,
              u16* __restrict__ out, long outZs, int R, int C)
{
    const int z = blockIdx.z;
    const int r0 = blockIdx.y * 64, c0 = blockIdx.x * 64;
    __shared__ u16 t[64][68];
    const int tx = threadIdx.x & 63, ty = threadIdx.x >> 6;
    if constexpr (INF32) {
        const float* in = (const float*)inp + (long)z * inZs;
#pragma unroll
        for (int i = 0; i < 16; i++) {
            const int r = i * 4 + ty;
            t[r][tx] = f2bf(in[(long)(r0 + r) * C + c0 + tx]);
        }
    } else {
        const u16* in = (const u16*)inp + (long)z * inZs;
#pragma unroll
        for (int i = 0; i < 16; i++) {
            const int r = i * 4 + ty;
            t[r][tx] = in[(long)(r0 + r) * C + c0 + tx];
        }
    }
    __syncthreads();
    u16* o = out + (long)z * outZs;
#pragma unroll
    for (int i = 0; i < 16; i++) {
        const int r = i * 4 + ty;
        o[(long)(c0 + r) * R + r0 + tx] = t[tx][r];
    }
}

// elementwise f32 -> bf16 (size multiple of 1024)
__global__ __launch_bounds__(256)
void cvt_k(const float* __restrict__ in, u16* __restrict__ out)
{
    const long i = (long)blockIdx.x * 256 + threadIdx.x;
    const float4 v = ((const float4*)in)[i];
    ushort4 o;
    o.x = f2bf(v.x); o.y = f2bf(v.y); o.z = f2bf(v.z); o.w = f2bf(v.w);
    ((ushort4*)out)[i] = o;
}

// ---------------------------------------------------------------------------
// LayerNorm rows of ND=256, f32 in -> bf16 out. One wave per row.
// ---------------------------------------------------------------------------
__global__ __launch_bounds__(256)
void ln_k(const float* __restrict__ x, const float* __restrict__ w,
          const float* __restrict__ b, u16* __restrict__ y)
{
    const int wid = threadIdx.x >> 6, lane = threadIdx.x & 63;
    const int row = blockIdx.x * 4 + wid;
    const float4 v = reinterpret_cast<const float4*>(x + (long)row * ND)[lane];
    float s = v.x + v.y + v.z + v.w;
#pragma unroll
    for (int o = 32; o >= 1; o >>= 1) s += __shfl_xor(s, o);
    const float mean = s * (1.f / ND);
    const float d0 = v.x - mean, d1 = v.y - mean, d2 = v.z - mean, d3 = v.w - mean;
    float sq = d0 * d0 + d1 * d1 + d2 * d2 + d3 * d3;
#pragma unroll
    for (int o = 32; o >= 1; o >>= 1) sq += __shfl_xor(sq, o);
    const float rstd = rsqrtf(sq * (1.f / ND) + 1e-5f);
    const float4 wv = reinterpret_cast<const float4*>(w)[lane];
    const float4 bv = reinterpret_cast<const float4*>(b)[lane];
    ushort4 o4;
    o4.x = f2bf(d0 * rstd * wv.x + bv.x);
    o4.y = f2bf(d1 * rstd * wv.y + bv.y);
    o4.z = f2bf(d2 * rstd * wv.z + bv.z);
    o4.w = f2bf(d3 * rstd * wv.w + bv.w);
    reinterpret_cast<ushort4*>(y + (long)row * ND)[lane] = o4;
}

// ---------------------------------------------------------------------------
// Row softmax, bf16 in place, f32 internal. grid (NN, 1, H).
// ---------------------------------------------------------------------------
__global__ __launch_bounds__(256)
void softmax_k(u16* __restrict__ sc, long zstride)
{
    u16* r = sc + (long)blockIdx.z * zstride + (long)blockIdx.x * NN;
    const int t = threadIdx.x;
    uint4 u = ((uint4*)r)[t];
    float f[8];
    f[0] = bf2f(u.x & 0xffff); f[1] = bf2f(u.x >> 16);
    f[2] = bf2f(u.y & 0xffff); f[3] = bf2f(u.y >> 16);
    f[4] = bf2f(u.z & 0xffff); f[5] = bf2f(u.z >> 16);
    f[6] = bf2f(u.w & 0xffff); f[7] = bf2f(u.w >> 16);
    float m = f[0];
#pragma unroll
    for (int i = 1; i < 8; i++) m = fmaxf(m, f[i]);
    __shared__ float red[4];
#pragma unroll
    for (int o = 32; o >= 1; o >>= 1) m = fmaxf(m, __shfl_xor(m, o));
    if ((t & 63) == 0) red[t >> 6] = m;
    __syncthreads();
    m = fmaxf(fmaxf(red[0], red[1]), fmaxf(red[2], red[3]));
    __syncthreads();
    float s = 0.f;
#pragma unroll
    for (int i = 0; i < 8; i++) { f[i] = expf(f[i] - m); s += f[i]; }
#pragma unroll
    for (int o = 32; o >= 1; o >>= 1) s += __shfl_xor(s, o);
    if ((t & 63) == 0) red[t >> 6] = s;
    __syncthreads();
    s = red[0] + red[1] + red[2] + red[3];
    const float inv = 1.f / s;
    uint4 w;
    w.x = (unsigned)f2bf(f[0] * inv) | ((unsigned)f2bf(f[1] * inv) << 16);
    w.y = (unsigned)f2bf(f[2] * inv) | ((unsigned)f2bf(f[3] * inv) << 16);
    w.z = (unsigned)f2bf(f[4] * inv) | ((unsigned)f2bf(f[5] * inv) << 16);
    w.w = (unsigned)f2bf(f[6] * inv) | ((unsigned)f2bf(f[7] * inv) << 16);
    ((uint4*)r)[t] = w;
}

// ---------------------------------------------------------------------------
// Edge-dot precompute, bf16 out: dtb[s][e][h] = bf16( evec_l[h,s,:] . e[e,:] )
// One 16B line per (s,e) serves all 8 heads. grid (EE/256, LMAX)
// ---------------------------------------------------------------------------
__global__ __launch_bounds__(256)
void dotsT_k(const u16* __restrict__ e, const float* __restrict__ evl,
             u16* __restrict__ dtb)
{
    const int s = blockIdx.y;
    const int ei = blockIdx.x * 256 + threadIdx.x;
    __shared__ float evs[H * ED];
    for (int i = threadIdx.x; i < H * ED; i += 256)
        evs[i] = evl[((i >> 7) * LMAX + s) * ED + (i & 127)];
    __syncthreads();
    const uint4* er = (const uint4*)(e + (long)ei * ED);
    float c[H];
#pragma unroll
    for (int h = 0; h < H; h++) c[h] = 0.f;
#pragma unroll
    for (int d8 = 0; d8 < ED / 8; d8++) {
        const uint4 q = er[d8];
        float f[8];
        f[0] = bf2f(q.x & 0xffff); f[1] = bf2f(q.x >> 16);
        f[2] = bf2f(q.y & 0xffff); f[3] = bf2f(q.y >> 16);
        f[4] = bf2f(q.z & 0xffff); f[5] = bf2f(q.z >> 16);
        f[6] = bf2f(q.w & 0xffff); f[7] = bf2f(q.w >> 16);
#pragma unroll
        for (int h = 0; h < H; h++) {
            const float* w = &evs[h * ED + d8 * 8];
            c[h] += w[0] * f[0] + w[1] * f[1] + w[2] * f[2] + w[3] * f[3]
                  + w[4] * f[4] + w[5] * f[5] + w[6] * f[6] + w[7] * f[7];
        }
    }
    uint4 o;
    o.x = (unsigned)f2bf(c[0]) | ((unsigned)f2bf(c[1]) << 16);
    o.y = (unsigned)f2bf(c[2]) | ((unsigned)f2bf(c[3]) << 16);
    o.z = (unsigned)f2bf(c[4]) | ((unsigned)f2bf(c[5]) << 16);
    o.w = (unsigned)f2bf(c[6]) | ((unsigned)f2bf(c[7]) << 16);
    *(uint4*)(dtb + ((long)s * EE + ei) * H) = o;
}

// ---------------------------------------------------------------------------
// Path compaction: pc0 = d | e0<<8 ; pc1 = e1|e2<<16 ; pc2 = e3|e4<<16
// (d<=6 fits 8b; edge ids < 32768 fit 15/16b). 12 B/pair SoA, L3-resident.
// ---------------------------------------------------------------------------
__global__ __launch_bounds__(256)
void pack_k(const int* __restrict__ ndist, const int* __restrict__ epaths,
            unsigned* __restrict__ pc0, unsigned* __restrict__ pc1,
            unsigned* __restrict__ pc2)
{
    const long idx = (long)blockIdx.x * 256 + threadIdx.x;
    const unsigned d = (unsigned)ndist[idx];
    const int* ep = epaths + idx * LMAX;
    const unsigned e0 = ep[0], e1 = ep[1], e2 = ep[2], e3 = ep[3], e4 = ep[4];
    pc0[idx] = d | (e0 << 8);
    pc1[idx] = e1 | (e2 << 16);
    pc2[idx] = e3 | (e4 << 16);
}

// ---------------------------------------------------------------------------
// Attention bias -> bf16 scores init: sc[h][n][m] = b_mat + c[h]
// Compact reads + 5 predicated independent 16B gathers (all heads at once).
// ---------------------------------------------------------------------------
__global__ __launch_bounds__(256)
void bias_k(const unsigned* __restrict__ pc0, const unsigned* __restrict__ pc1,
            const unsigned* __restrict__ pc2, const float* __restrict__ bspat,
            const u16* __restrict__ dtb, u16* __restrict__ sc)
{
    const long idx = (long)blockIdx.x * 256 + threadIdx.x;
    const unsigned w0 = pc0[idx], w1 = pc1[idx], w2 = pc2[idx];
    const int d = (int)(w0 & 255u);
    float bb = 0.f;
    if (d > 0) bb = bspat[(d < LMAX ? d : LMAX) - 1];
    int npe = d - 1;
    npe = npe < 0 ? 0 : (npe > LMAX ? LMAX : npe);
    const int ep[LMAX] = { (int)(w0 >> 8), (int)(w1 & 0xffffu), (int)(w1 >> 16),
                           (int)(w2 & 0xffffu), (int)(w2 >> 16) };
    float c[H];
#pragma unroll
    for (int h = 0; h < H; h++) c[h] = 0.f;
#pragma unroll
    for (int s = 0; s < LMAX; s++) {
        if (s < npe) {   // predicated; 5 independent gather addresses -> ILP
            const uint4 q = *(const uint4*)(dtb + ((long)s * EE + ep[s]) * H);
            c[0] += bf2f(q.x & 0xffff); c[1] += bf2f(q.x >> 16);
            c[2] += bf2f(q.y & 0xffff); c[3] += bf2f(q.y >> 16);
            c[4] += bf2f(q.z & 0xffff); c[5] += bf2f(q.z >> 16);
            c[6] += bf2f(q.w & 0xffff); c[7] += bf2f(q.w >> 16);
        }
    }
    const float inv = npe > 0 ? 1.f / (float)npe : 0.f;
    const long NN2 = (long)NN * NN;
#pragma unroll
    for (int h = 0; h < H; h++)
        sc[(long)h * NN2 + idx] = f2bf(bb + c[h] * inv);
}

__global__ void deg_k(const int* __restrict__ ei, int* __restrict__ ind,
                      int* __restrict__ outd)
{
    const int e = blockIdx.x * 256 + threadIdx.x;
    atomicAdd(&outd[ei[e]], 1);        // edge_index[0] = src
    atomicAdd(&ind[ei[EE + e]], 1);    // edge_index[1] = dst
}

__global__ void degembed_k(float* __restrict__ h, const int* __restrict__ ind,
                           const int* __restrict__ outd,
                           const float* __restrict__ z_in,
                           const float* __restrict__ z_out)
{
    const int idx = blockIdx.x * 256 + threadIdx.x;
    const int n = idx >> 8, c = idx & 255;
    int di = ind[n];  di = di > (MAXDEG - 1) ? (MAXDEG - 1) : di;
    int dw = outd[n]; dw = dw > (MAXDEG - 1) ? (MAXDEG - 1) : dw;
    h[idx] += z_in[di * ND + c] + z_out[dw * ND + c];
}

__global__ void sentinel_k(float* o) { o[0] = 12345.0f; }  // ws too small marker

// ---------------------------------------------------------------------------
extern "C" void kernel_launch(void* const* d_in, const int* in_sizes, int n_in,
                              void* d_out, int out_size, void* d_ws, size_t ws_size,
                              hipStream_t stream)
{
    const float* x      = (const float*)d_in[0];
    const int*   eidx   = (const int*)d_in[1];
    const float* eattr  = (const float*)d_in[2];
    const int*   ndist  = (const int*)d_in[3];
    const int*   epaths = (const int*)d_in[4];
    const float* Wn_in  = (const float*)d_in[5];
    const float* bn_in  = (const float*)d_in[6];
    const float* We_in  = (const float*)d_in[7];
    const float* be_in  = (const float*)d_in[8];
    const float* z_in   = (const float*)d_in[9];
    const float* z_out  = (const float*)d_in[10];
    const float* bspat  = (const float*)d_in[11];
    const float* ln1w   = (const float*)d_in[12];
    const float* ln1b   = (const float*)d_in[13];
    const float* ln2w   = (const float*)d_in[14];
    const float* ln2b   = (const float*)d_in[15];
    const float* Wq     = (const float*)d_in[16];
    const float* bq     = (const float*)d_in[17];
    const float* Wk     = (const float*)d_in[18];
    const float* bk     = (const float*)d_in[19];
    const float* Wv     = (const float*)d_in[20];
    const float* bv     = (const float*)d_in[21];
    const float* evec   = (const float*)d_in[22];
    const float* Wo     = (const float*)d_in[23];
    const float* bo     = (const float*)d_in[24];
    const float* Wff1   = (const float*)d_in[25];
    const float* bff1   = (const float*)d_in[26];
    const float* Wff2   = (const float*)d_in[27];
    const float* bff2   = (const float*)d_in[28];
    const float* Wout   = (const float*)d_in[29];
    const float* bout   = (const float*)d_in[30];
    float* out = (float*)d_out;

    // ---- workspace carve-up ----
    char* p = (char*)d_ws;
    auto alloc = [&](size_t bytes) -> char* {
        char* r = p;
        p += (bytes + 255) & ~(size_t)255;
        return r;
    };
    float* h    = (float*)alloc((size_t)NN * ND * 4);
    u16*   hb   = (u16*)alloc((size_t)NN * ND * 2);
    u16*   xb   = (u16*)alloc((size_t)NN * IN_ND * 2);
    u16*   xnb  = (u16*)alloc((size_t)NN * ND * 2);
    u16*   eb   = (u16*)alloc((size_t)EE * IN_ED * 2);
    u16*   e_bf = (u16*)alloc((size_t)EE * ED * 2);
    u16*   qb   = (u16*)alloc((size_t)NN * H * ND * 2);
    u16*   kb   = (u16*)alloc((size_t)NN * H * ND * 2);
    u16*   vb   = (u16*)alloc((size_t)NN * H * ND * 2);
    u16*   vT   = (u16*)alloc((size_t)NN * H * ND * 2);       // [h*256+d][m]
    u16*   o2   = (u16*)alloc((size_t)NN * H * ND * 2);
    u16*   ff1b = (u16*)alloc((size_t)NN * FF * 2);
    u16*   dtb  = (u16*)alloc((size_t)LMAX * EE * H * 2);     // [s][e][h] bf16
    u16*   WqT  = (u16*)alloc((size_t)NL * H * ND * ND * 2);
    u16*   WkT  = (u16*)alloc((size_t)NL * H * ND * ND * 2);
    u16*   WvT  = (u16*)alloc((size_t)NL * H * ND * ND * 2);
    u16*   WoT  = (u16*)alloc((size_t)NL * ND * H * ND * 2);
    u16*   W1T  = (u16*)alloc((size_t)NL * FF * ND * 2);
    u16*   W2T  = (u16*)alloc((size_t)NL * ND * FF * 2);
    u16*   WnT  = (u16*)alloc((size_t)ND * IN_ND * 2);
    u16*   WeT  = (u16*)alloc((size_t)ED * IN_ED * 2);
    u16*   WouT = (u16*)alloc((size_t)ND * ND * 2);
    int*   ind  = (int*)alloc(NN * 4);
    int*   outd = (int*)alloc(NN * 4);
    unsigned* pc0 = (unsigned*)alloc((size_t)NN * NN * 4);    // 16.8 MB
    unsigned* pc1 = (unsigned*)alloc((size_t)NN * NN * 4);
    unsigned* pc2 = (unsigned*)alloc((size_t)NN * NN * 4);
    u16*   sc   = (u16*)alloc((size_t)H * NN * NN * 2);       // 67 MB bf16
    if ((size_t)(p - (char*)d_ws) > ws_size) {
        sentinel_k<<<1, 1, 0, stream>>>(out);
        return;
    }

    const long NN2 = (long)NN * NN;
    const float* nul = nullptr;

    // ---- degrees + path compaction ----
    hipMemsetAsync(ind, 0, NN * 4, stream);
    hipMemsetAsync(outd, 0, NN * 4, stream);
    deg_k<<<EE / 256, 256, 0, stream>>>(eidx, ind, outd);
    pack_k<<<(int)(NN2 / 256), 256, 0, stream>>>(ndist, epaths, pc0, pc1, pc2);

    // ---- input converts + weight transposes (bf16) ----
    cvt_k<<<NN * IN_ND / 1024, 256, 0, stream>>>(x, xb);
    cvt_k<<<EE * IN_ED / 1024, 256, 0, stream>>>(eattr, eb);
    transp_k<1><<<dim3(4, 4, NL * H), 256, 0, stream>>>(Wq, ND * ND, WqT, ND * ND, ND, ND);
    transp_k<1><<<dim3(4, 4, NL * H), 256, 0, stream>>>(Wk, ND * ND, WkT, ND * ND, ND, ND);
    transp_k<1><<<dim3(4, 4, NL * H), 256, 0, stream>>>(Wv, ND * ND, WvT, ND * ND, ND, ND);
    transp_k<1><<<dim3(4, 32, NL), 256, 0, stream>>>(Wo, (long)H * ND * ND, WoT, (long)H * ND * ND, H * ND, ND);
    transp_k<1><<<dim3(16, 4, NL), 256, 0, stream>>>(Wff1, (long)ND * FF, W1T, (long)ND * FF, ND, FF);
    transp_k<1><<<dim3(4, 16, NL), 256, 0, stream>>>(Wff2, (long)ND * FF, W2T, (long)ND * FF, FF, ND);
    transp_k<1><<<dim3(4, 2, 1), 256, 0, stream>>>(Wn_in, 0, WnT, 0, IN_ND, ND);
    transp_k<1><<<dim3(2, 1, 1), 256, 0, stream>>>(We_in, 0, WeT, 0, IN_ED, ED);
    transp_k<1><<<dim3(4, 4, 1), 256, 0, stream>>>(Wout, 0, WouT, 0, ND, ND);

    // ---- input projections ----
    mgemm_k<E_BIAS, 0><<<dim3(2, 16), 256, 0, stream>>>(
        xb, IN_ND, 0, WnT, IN_ND, 0, h, ND, 0, IN_ND, bn_in, 1.f);
    degembed_k<<<NN * ND / 256, 256, 0, stream>>>(h, ind, outd, z_in, z_out);
    mgemm_k<E_BIAS, 1><<<dim3(1, EE / 128), 256, 0, stream>>>(
        eb, IN_ED, 0, WeT, IN_ED, 0, e_bf, ED, 0, IN_ED, be_in, 1.f);

    const float scale = 1.f / 16.f;  // 1/sqrt(dk=256)

    for (int l = 0; l < NL; l++) {
        ln_k<<<NN / 4, 256, 0, stream>>>(h, ln1w + l * ND, ln1b + l * ND, xnb);

        mgemm_k<E_BIAS, 1><<<dim3(16, 16), 256, 0, stream>>>(
            xnb, ND, 0, WqT + (size_t)l * H * ND * ND, ND, 0,
            qb, H * ND, 0, ND, bq + l * H * ND, 1.f);
        mgemm_k<E_BIAS, 1><<<dim3(16, 16), 256, 0, stream>>>(
            xnb, ND, 0, WkT + (size_t)l * H * ND * ND, ND, 0,
            kb, H * ND, 0, ND, bk + l * H * ND, 1.f);
        mgemm_k<E_BIAS, 1><<<dim3(16, 16), 256, 0, stream>>>(
            xnb, ND, 0, WvT + (size_t)l * H * ND * ND, ND, 0,
            vb, H * ND, 0, ND, bv + l * H * ND, 1.f);
        transp_k<0><<<dim3(32, 32, 1), 256, 0, stream>>>(
            vb, 0, vT, 0, NN, H * ND);

        dotsT_k<<<dim3(EE / 256, LMAX), 256, 0, stream>>>(
            e_bf, evec + (size_t)l * H * LMAX * ED, dtb);
        bias_k<<<(int)(NN2 / 256), 256, 0, stream>>>(pc0, pc1, pc2, bspat, dtb, sc);

        // QK^T accumulating onto bias (bf16 C)
        mgemm_k<E_ACC, 1><<<dim3(16, 16, H), 256, 0, stream>>>(
            qb, H * ND, ND, kb, H * ND, ND, sc, NN, NN2, ND, nul, scale);
        softmax_k<<<dim3(NN, 1, H), 256, 0, stream>>>(sc, NN2);
        // PV: A = probs (bf16), B = vT
        mgemm_k<E_NONE, 1><<<dim3(2, 16, H), 256, 0, stream>>>(
            sc, NN, NN2, vT, NN, (long)ND * NN, o2, H * ND, ND, NN, nul, 1.f);

        // h = o2 @ Wo + bo + h
        mgemm_k<E_BIAS_RES, 0><<<dim3(2, 16), 256, 0, stream>>>(
            o2, H * ND, 0, WoT + (size_t)l * ND * H * ND, H * ND, 0,
            h, ND, 0, H * ND, bo + l * ND, 1.f);

        ln_k<<<NN / 4, 256, 0, stream>>>(h, ln2w + l * ND, ln2b + l * ND, xnb);
        mgemm_k<E_BIAS_GELU, 1><<<dim3(8, 16), 256, 0, stream>>>(
            xnb, ND, 0, W1T + (size_t)l * FF * ND, ND, 0,
            ff1b, FF, 0, ND, bff1 + l * FF, 1.f);
        mgemm_k<E_BIAS_RES, 0><<<dim3(2, 16), 256, 0, stream>>>(
            ff1b, FF, 0, W2T + (size_t)l * ND * FF, FF, 0,
            h, ND, 0, FF, bff2 + l * ND, 1.f);
    }

    cvt_k<<<NN * ND / 1024, 256, 0, stream>>>(h, hb);
    mgemm_k<E_BIAS, 0><<<dim3(2, 16), 256, 0, stream>>>(
        hb, ND, 0, WouT, ND, 0, out, ND, 0, ND, bout, 1.f);
}